// Round 1
// baseline (1681.113 us; speedup 1.0000x reference)
//
#include <hip/hip_runtime.h>
#include <math.h>

#define BB 16
#define LL 128
#define D_IN 8
#define HH 128
#define NLAYER 2
#define FUT 12
#define MDIM 2

// ---------------- ts cumsum (inclusive) ----------------
__global__ __launch_bounds__(LL) void k_ts(const float* __restrict__ hist, float* __restrict__ ts) {
    int b = blockIdx.x, j = threadIdx.x;
    __shared__ float s[LL];
    s[j] = fmaxf(hist[(b * LL + j) * D_IN + 5], 0.f);
    __syncthreads();
    for (int d = 1; d < LL; d <<= 1) {
        float add = (j >= d) ? s[j - d] : 0.f;
        __syncthreads();
        s[j] += add;
        __syncthreads();
    }
    ts[b * LL + j] = s[j];
}

// ---------------- h0 = (hist @ Wp + bp) * vm ----------------
__global__ __launch_bounds__(256) void k_h0(const float* __restrict__ hist, const float* __restrict__ mask,
                                            const float* __restrict__ Wp, const float* __restrict__ bp,
                                            float* __restrict__ h) {
    int idx = blockIdx.x * 256 + threadIdx.x;
    if (idx >= BB * LL * HH) return;
    int k = idx & (HH - 1);
    int bi = idx >> 7;
    const float* hr = hist + (size_t)bi * D_IN;
    float acc = bp[k];
#pragma unroll
    for (int f = 0; f < D_IN; f++) acc += hr[f] * Wp[f * HH + k];
    float vm = mask[bi] > 0.f ? 1.f : 0.f;
    h[idx] = acc * vm;
}

// ---------------- composed matrices: A_mat = We2@Wa1[2H:], M_mat = We2@Wm1[H:], consts ----------------
__global__ __launch_bounds__(HH) void k_compose(const float* __restrict__ We2, const float* __restrict__ be2,
                                                const float* __restrict__ Wa1, const float* __restrict__ ba1,
                                                const float* __restrict__ Wm1, const float* __restrict__ bm1,
                                                float* __restrict__ Amat, float* __restrict__ Mmat,
                                                float* __restrict__ ca, float* __restrict__ cm, int l) {
    int p = blockIdx.x, q = threadIdx.x;
    __shared__ float row[HH];
    const float* WaE = Wa1 + (size_t)(l * 3 * HH + 2 * HH) * HH;
    const float* WmE = Wm1 + (size_t)(l * 2 * HH + HH) * HH;
    if (p < HH) {
        row[q] = We2[(size_t)(l * HH + p) * HH + q];
        __syncthreads();
        float a = 0.f, m = 0.f;
        for (int k = 0; k < HH; k++) { float w = row[k]; a += w * WaE[k * HH + q]; m += w * WmE[k * HH + q]; }
        Amat[p * HH + q] = a;
        Mmat[p * HH + q] = m;
    } else {
        row[q] = be2[l * HH + q];
        __syncthreads();
        float a = 0.f, m = 0.f;
        for (int k = 0; k < HH; k++) { float w = row[k]; a += w * WaE[k * HH + q]; m += w * WmE[k * HH + q]; }
        ca[q] = a + ba1[l * HH + q];
        cm[q] = m + bm1[l * HH + q];
    }
}

// ---------------- per-(b,i) projections: sa, da, ma, oa ----------------
__global__ __launch_bounds__(256) void k_pre(const float* __restrict__ h, const float* __restrict__ Wa1,
                                             const float* __restrict__ Wm1, const float* __restrict__ Wo1,
                                             float* __restrict__ sa, float* __restrict__ da,
                                             float* __restrict__ ma, float* __restrict__ oa, int l) {
    int bi = blockIdx.x, tid = threadIdx.x;
    __shared__ float hs[HH];
    if (tid < HH) hs[tid] = h[(size_t)bi * HH + tid];
    __syncthreads();
    for (int o = tid; o < 4 * HH; o += 256) {
        int m = o >> 7, k = o & (HH - 1);
        const float* W;
        float* dst;
        if (m == 0)      { W = Wa1 + (size_t)(l * 3 * HH) * HH;        dst = sa; }
        else if (m == 1) { W = Wa1 + (size_t)(l * 3 * HH + HH) * HH;   dst = da; }
        else if (m == 2) { W = Wm1 + (size_t)(l * 2 * HH) * HH;        dst = ma; }
        else             { W = Wo1 + (size_t)(l * 2 * HH) * HH;        dst = oa; }
        float acc = 0.f;
        for (int kk = 0; kk < HH; kk++) acc += hs[kk] * W[kk * HH + k];
        dst[(size_t)bi * HH + k] = acc;
    }
}

// ---------------- main fused attention/message kernel: one block per (b,i) ----------------
__global__ __launch_bounds__(256) void k_attn(
    const float* __restrict__ hist, const float* __restrict__ mask, const float* __restrict__ ts,
    const float* __restrict__ sa, const float* __restrict__ da, const float* __restrict__ ma,
    const float* __restrict__ Amat, const float* __restrict__ Mmat,
    const float* __restrict__ ca, const float* __restrict__ cm,
    const float* __restrict__ wa2, const float* __restrict__ ba2,
    const float* __restrict__ Wm2, const float* __restrict__ bm2,
    const float* __restrict__ We1, const float* __restrict__ be1,
    float* __restrict__ agg, int l) {
    __shared__ float ef_s[LL * 5];
    __shared__ float tsl[LL * 17];
    __shared__ float A_s[4 * 16 * 33];
    __shared__ float lat_s[LL], lon_s[LL], tss_s[LL], src_s[LL], val_s[LL];
    __shared__ float sa_s[HH], ca_s[HH], cm_s[HH], ma_s[HH], wa2_s[HH];
    __shared__ float att4[LL * 4];   // reused as v4 [4][128] in phase 2
    __shared__ float w_s[LL], red_s[LL], v_s[HH];

    const int tid = threadIdx.x;
    const int bi = blockIdx.x;
    const int b = bi >> 7, i = bi & (LL - 1);
    const float* We1l = We1 + l * 4 * HH;
    const float* be1l = be1 + l * HH;

    if (tid < LL) {
        int bj = b * LL + tid;
        lat_s[tid] = hist[(size_t)bj * D_IN + 0];
        lon_s[tid] = hist[(size_t)bj * D_IN + 1];
        src_s[tid] = hist[(size_t)bj * D_IN + 6];
        tss_s[tid] = ts[bj];
        val_s[tid] = mask[bj];
        sa_s[tid]  = sa[(size_t)bi * HH + tid];
        ma_s[tid]  = ma[(size_t)bi * HH + tid];
        ca_s[tid]  = ca[tid];
        cm_s[tid]  = cm[tid];
        wa2_s[tid] = wa2[l * HH + tid];
    }
    __syncthreads();
    // edge features for this query i, all j
    if (tid < LL) {
        int j = tid;
        float dlat = lat_s[i] - lat_s[j], dlon = lon_s[i] - lon_s[j];
        ef_s[j * 5 + 0] = sqrtf(dlat * dlat + dlon * dlon + 1e-8f);
        ef_s[j * 5 + 1] = fabsf(tss_s[i] - tss_s[j]) * (1.f / 300.f);
        ef_s[j * 5 + 2] = (src_s[i] == src_s[j]) ? 1.f : 0.f;
        ef_s[j * 5 + 3] = (i == j) ? 1.f : 0.f;
    }
    __syncthreads();

    const int p = tid >> 2, q = tid & 3;
    const int j0 = p * 2, j1 = p * 2 + 1;
    const int kbase = q * 32;
    const int jt = tid >> 1, rb = (tid & 1) * 8;  // t-slice staging assignment
    const float efa = ef_s[jt * 5 + 0], efb = ef_s[jt * 5 + 1], efc = ef_s[jt * 5 + 2], efd = ef_s[jt * 5 + 3];
    const int cbase = (tid & 15) * 8, rstage = tid >> 4;

    float u0[32], u1[32];

    // ================= phase 1: U_a = t @ Amat -> att =================
#pragma unroll
    for (int x = 0; x < 32; x++) { u0[x] = 0.f; u1[x] = 0.f; }
    for (int kc = 0; kc < HH; kc += 16) {
        __syncthreads();
#pragma unroll
        for (int e = 0; e < 8; e++) {
            int c = cbase + e;
            A_s[(c >> 5) * 528 + rstage * 33 + (c & 31)] = Amat[(kc + rstage) * HH + c];
        }
#pragma unroll
        for (int e = 0; e < 8; e++) {
            int r = rb + e, k = kc + r;
            float v = efa * We1l[k] + efb * We1l[HH + k] + efc * We1l[2 * HH + k] + efd * We1l[3 * HH + k] + be1l[k];
            tsl[jt * 17 + r] = fmaxf(v, 0.f);
        }
        __syncthreads();
#pragma unroll
        for (int r = 0; r < 16; r++) {
            float t0 = tsl[j0 * 17 + r], t1 = tsl[j1 * 17 + r];
            const float* Ar = A_s + q * 528 + r * 33;
#pragma unroll
            for (int x = 0; x < 32; x++) { float a = Ar[x]; u0[x] += t0 * a; u1[x] += t1 * a; }
        }
    }
    // att partials
    {
        const float* da0 = da + (size_t)(b * LL + j0) * HH + kbase;
        const float* da1 = da + (size_t)(b * LL + j1) * HH + kbase;
        float ap0 = 0.f, ap1 = 0.f;
#pragma unroll
        for (int x = 0; x < 32; x++) {
            int k = kbase + x;
            float base = sa_s[k] + ca_s[k];
            ap0 += tanhf(base + da0[x] + u0[x]) * wa2_s[k];
            ap1 += tanhf(base + da1[x] + u1[x]) * wa2_s[k];
        }
        att4[j0 * 4 + q] = ap0;
        att4[j1 * 4 + q] = ap1;
    }
    __syncthreads();
    // finalize att + softmax over j
    const float inv = 1.0f / sqrtf((float)HH);
    if (tid < LL) {
        float a = (att4[tid * 4 + 0] + att4[tid * 4 + 1] + att4[tid * 4 + 2] + att4[tid * 4 + 3] + ba2[l]) * inv;
        if (!(val_s[tid] > 0.f)) a = -1e9f;
        if (!(val_s[i] > 0.f)) a = -1e9f;
        w_s[tid] = a;
        red_s[tid] = a;
    }
    __syncthreads();
    for (int s = 64; s > 0; s >>= 1) { if (tid < s) red_s[tid] = fmaxf(red_s[tid], red_s[tid + s]); __syncthreads(); }
    float mx = red_s[0];
    __syncthreads();
    if (tid < LL) { float e = expf(w_s[tid] - mx); w_s[tid] = e; red_s[tid] = e; }
    __syncthreads();
    for (int s = 64; s > 0; s >>= 1) { if (tid < s) red_s[tid] += red_s[tid + s]; __syncthreads(); }
    float denom = red_s[0];
    __syncthreads();
    if (tid < LL) w_s[tid] = w_s[tid] / denom;

    // ================= phase 2: U_m = t @ Mmat -> weighted msg_in sum -> agg =================
#pragma unroll
    for (int x = 0; x < 32; x++) { u0[x] = 0.f; u1[x] = 0.f; }
    for (int kc = 0; kc < HH; kc += 16) {
        __syncthreads();
#pragma unroll
        for (int e = 0; e < 8; e++) {
            int c = cbase + e;
            A_s[(c >> 5) * 528 + rstage * 33 + (c & 31)] = Mmat[(kc + rstage) * HH + c];
        }
#pragma unroll
        for (int e = 0; e < 8; e++) {
            int r = rb + e, k = kc + r;
            float v = efa * We1l[k] + efb * We1l[HH + k] + efc * We1l[2 * HH + k] + efd * We1l[3 * HH + k] + be1l[k];
            tsl[jt * 17 + r] = fmaxf(v, 0.f);
        }
        __syncthreads();
#pragma unroll
        for (int r = 0; r < 16; r++) {
            float t0 = tsl[j0 * 17 + r], t1 = tsl[j1 * 17 + r];
            const float* Ar = A_s + q * 528 + r * 33;
#pragma unroll
            for (int x = 0; x < 32; x++) { float a = Ar[x]; u0[x] += t0 * a; u1[x] += t1 * a; }
        }
    }
    // msg_in = relu(ma + U_m + cm); weighted sum over j into u0
    {
        float wj0 = w_s[j0], wj1 = w_s[j1];
#pragma unroll
        for (int x = 0; x < 32; x++) {
            int k = kbase + x;
            float base = ma_s[k] + cm_s[k];
            float m0 = fmaxf(base + u0[x], 0.f);
            float m1 = fmaxf(base + u1[x], 0.f);
            u0[x] = wj0 * m0 + wj1 * m1;
        }
    }
    // butterfly over the 16 p-groups within each wave (lane bits 2..5)
#pragma unroll
    for (int x = 0; x < 32; x++) {
        u0[x] += __shfl_xor(u0[x], 4);
        u0[x] += __shfl_xor(u0[x], 8);
        u0[x] += __shfl_xor(u0[x], 16);
        u0[x] += __shfl_xor(u0[x], 32);
    }
    {
        float* v4 = att4;  // reuse: [4 waves][128]
        if ((tid & 63) < 4) {
            int w = tid >> 6;
#pragma unroll
            for (int x = 0; x < 32; x++) v4[w * 128 + kbase + x] = u0[x];
        }
    }
    __syncthreads();
    if (tid < HH) {
        float* v4 = att4;
        v_s[tid] = v4[tid] + v4[128 + tid] + v4[256 + tid] + v4[384 + tid];
    }
    __syncthreads();
    if (tid < HH) {
        const float* Wm2l = Wm2 + (size_t)l * HH * HH;
        float acc = bm2[l * HH + tid];
        for (int kk = 0; kk < HH; kk++) acc += v_s[kk] * Wm2l[kk * HH + tid];
        agg[(size_t)bi * HH + tid] = acc;
    }
}

// ---------------- out MLP + residual + LayerNorm ----------------
__global__ __launch_bounds__(HH) void k_post(const float* __restrict__ h, const float* __restrict__ oa,
                                             const float* __restrict__ agg, const float* __restrict__ mask,
                                             const float* __restrict__ Wo1, const float* __restrict__ bo1,
                                             const float* __restrict__ Wo2, const float* __restrict__ bo2,
                                             const float* __restrict__ ln_g, const float* __restrict__ ln_b,
                                             float* __restrict__ hout, int l) {
    int bi = blockIdx.x, k = threadIdx.x;
    __shared__ float ag_s[HH], g_s[HH], hs[HH], red[HH];
    ag_s[k] = agg[(size_t)bi * HH + k];
    hs[k] = h[(size_t)bi * HH + k];
    __syncthreads();
    const float* W1 = Wo1 + (size_t)(l * 2 * HH + HH) * HH;
    float x1 = oa[(size_t)bi * HH + k] + bo1[l * HH + k];
    for (int kk = 0; kk < HH; kk++) x1 += ag_s[kk] * W1[kk * HH + k];
    g_s[k] = fmaxf(x1, 0.f);
    __syncthreads();
    const float* W2 = Wo2 + (size_t)l * HH * HH;
    float o = bo2[l * HH + k];
    for (int kk = 0; kk < HH; kk++) o += g_s[kk] * W2[kk * HH + k];
    float y = hs[k] + o;
    red[k] = y;
    __syncthreads();
    for (int s = 64; s > 0; s >>= 1) { if (k < s) red[k] += red[k + s]; __syncthreads(); }
    float mu = red[0] / HH;
    __syncthreads();
    float d = y - mu;
    red[k] = d * d;
    __syncthreads();
    for (int s = 64; s > 0; s >>= 1) { if (k < s) red[k] += red[k + s]; __syncthreads(); }
    float var = red[0] / HH;
    float vm = mask[bi] > 0.f ? 1.f : 0.f;
    hout[(size_t)bi * HH + k] = ((y - mu) * rsqrtf(var + 1e-5f) * ln_g[l * HH + k] + ln_b[l * HH + k]) * vm;
}

// ---------------- decoder ----------------
__global__ __launch_bounds__(HH) void k_dec(const float* __restrict__ hist, const float* __restrict__ mask,
                                            const float* __restrict__ h, const float* __restrict__ hg,
                                            const float* __restrict__ hb, const float* __restrict__ Wh1,
                                            const float* __restrict__ bh1, const float* __restrict__ Wh2,
                                            const float* __restrict__ bh2, float* __restrict__ out) {
    int b = blockIdx.x, t = threadIdx.x;
    const int N = D_IN + HH;  // 136
    __shared__ float red[HH], x_s[D_IN + HH], u_s[HH];
    red[t] = mask[b * LL + t];
    __syncthreads();
    for (int s = 64; s > 0; s >>= 1) { if (t < s) red[t] += red[t + s]; __syncthreads(); }
    int vc = (int)red[0];
    vc = min(max(vc, 1), LL);
    int last = vc - 1;
    __syncthreads();
    if (t < D_IN) x_s[t] = hist[(size_t)(b * LL + last) * D_IN + t];
    x_s[D_IN + t] = h[(size_t)(b * LL + last) * HH + t];
    __syncthreads();
    float ps = 0.f;
    for (int f = t; f < N; f += HH) ps += x_s[f];
    red[t] = ps;
    __syncthreads();
    for (int s = 64; s > 0; s >>= 1) { if (t < s) red[t] += red[t + s]; __syncthreads(); }
    float mu = red[0] / N;
    __syncthreads();
    ps = 0.f;
    for (int f = t; f < N; f += HH) { float d = x_s[f] - mu; ps += d * d; }
    red[t] = ps;
    __syncthreads();
    for (int s = 64; s > 0; s >>= 1) { if (t < s) red[t] += red[t + s]; __syncthreads(); }
    float var = red[0] / N;
    float rs = rsqrtf(var + 1e-5f);
    __syncthreads();
    for (int f = t; f < N; f += HH) x_s[f] = (x_s[f] - mu) * rs * hg[f] + hb[f];
    __syncthreads();
    float acc = bh1[t];
    for (int f = 0; f < N; f++) acc += x_s[f] * Wh1[f * HH + t];
    u_s[t] = fmaxf(acc, 0.f);
    __syncthreads();
    if (t < FUT * MDIM) {
        float o = bh2[t];
        for (int k = 0; k < HH; k++) o += u_s[k] * Wh2[k * FUT * MDIM + t];
        if (isnan(o)) o = 0.f;
        else if (isinf(o)) o = (o > 0.f) ? 1e4f : -1e4f;
        out[b * FUT * MDIM + t] = o;
    }
}

// ---------------- copy h to output ----------------
__global__ __launch_bounds__(256) void k_copy(const float* __restrict__ h, float* __restrict__ out) {
    int idx = blockIdx.x * 256 + threadIdx.x;
    if (idx < BB * LL * HH) out[BB * FUT * MDIM + idx] = h[idx];
}

extern "C" void kernel_launch(void* const* d_in, const int* in_sizes, int n_in,
                              void* d_out, int out_size, void* d_ws, size_t ws_size,
                              hipStream_t stream) {
    const float* hist = (const float*)d_in[0];
    const float* mask = (const float*)d_in[1];
    const float* Wp  = (const float*)d_in[2];
    const float* bp  = (const float*)d_in[3];
    const float* We1 = (const float*)d_in[4];
    const float* be1 = (const float*)d_in[5];
    const float* We2 = (const float*)d_in[6];
    const float* be2 = (const float*)d_in[7];
    const float* Wa1 = (const float*)d_in[8];
    const float* ba1 = (const float*)d_in[9];
    const float* wa2 = (const float*)d_in[10];
    const float* ba2 = (const float*)d_in[11];
    const float* Wm1 = (const float*)d_in[12];
    const float* bm1 = (const float*)d_in[13];
    const float* Wm2 = (const float*)d_in[14];
    const float* bm2 = (const float*)d_in[15];
    const float* Wo1 = (const float*)d_in[16];
    const float* bo1 = (const float*)d_in[17];
    const float* Wo2 = (const float*)d_in[18];
    const float* bo2 = (const float*)d_in[19];
    const float* ln_g = (const float*)d_in[20];
    const float* ln_b = (const float*)d_in[21];
    const float* hg  = (const float*)d_in[22];
    const float* hb  = (const float*)d_in[23];
    const float* Wh1 = (const float*)d_in[24];
    const float* bh1 = (const float*)d_in[25];
    const float* Wh2 = (const float*)d_in[26];
    const float* bh2 = (const float*)d_in[27];
    float* out = (float*)d_out;

    float* ws = (float*)d_ws;
    float* ts_w  = ws; ws += BB * LL;
    float* h_w   = ws; ws += BB * LL * HH;
    float* sa_w  = ws; ws += BB * LL * HH;
    float* da_w  = ws; ws += BB * LL * HH;
    float* ma_w  = ws; ws += BB * LL * HH;
    float* oa_w  = ws; ws += BB * LL * HH;
    float* agg_w = ws; ws += BB * LL * HH;
    float* Am_w  = ws; ws += HH * HH;
    float* Mm_w  = ws; ws += HH * HH;
    float* ca_w  = ws; ws += HH;
    float* cm_w  = ws; ws += HH;

    k_ts<<<BB, LL, 0, stream>>>(hist, ts_w);
    k_h0<<<(BB * LL * HH + 255) / 256, 256, 0, stream>>>(hist, mask, Wp, bp, h_w);
    for (int l = 0; l < NLAYER; l++) {
        k_compose<<<HH + 1, HH, 0, stream>>>(We2, be2, Wa1, ba1, Wm1, bm1, Am_w, Mm_w, ca_w, cm_w, l);
        k_pre<<<BB * LL, 256, 0, stream>>>(h_w, Wa1, Wm1, Wo1, sa_w, da_w, ma_w, oa_w, l);
        k_attn<<<BB * LL, 256, 0, stream>>>(hist, mask, ts_w, sa_w, da_w, ma_w, Am_w, Mm_w, ca_w, cm_w,
                                            wa2, ba2, Wm2, bm2, We1, be1, agg_w, l);
        k_post<<<BB * LL, HH, 0, stream>>>(h_w, oa_w, agg_w, mask, Wo1, bo1, Wo2, bo2, ln_g, ln_b, h_w, l);
    }
    k_dec<<<BB, HH, 0, stream>>>(hist, mask, h_w, hg, hb, Wh1, bh1, Wh2, bh2, out);
    k_copy<<<(BB * LL * HH + 255) / 256, 256, 0, stream>>>(h_w, out);
}

// Round 2
// 478.945 us; speedup vs baseline: 3.5100x; 3.5100x over previous
//
#include <hip/hip_runtime.h>
#include <math.h>

#define BB 16
#define LL 128
#define D_IN 8
#define HH 128
#define NLAYER 2
#define FUT 12
#define MDIM 2

typedef __attribute__((ext_vector_type(8))) __bf16 bf16x8;
typedef __attribute__((ext_vector_type(8))) short short8v;
typedef __attribute__((ext_vector_type(4))) float f32x4;

#define MFMA_B16(A, B, C) __builtin_amdgcn_mfma_f32_16x16x32_bf16(A, B, C, 0, 0, 0)

static __device__ __forceinline__ short f2bf(float f) {
    union { float f; unsigned u; } v; v.f = f;
    unsigned r = v.u + 0x7FFFu + ((v.u >> 16) & 1u);
    return (short)(r >> 16);
}

static __device__ __forceinline__ float tanh_fast(float x) {
    float e = __expf(2.f * x);
    return 1.f - 2.f / (e + 1.f);
}

// ---------------- ts cumsum (inclusive) ----------------
__global__ __launch_bounds__(LL) void k_ts(const float* __restrict__ hist, float* __restrict__ ts) {
    int b = blockIdx.x, j = threadIdx.x;
    __shared__ float s[LL];
    s[j] = fmaxf(hist[(b * LL + j) * D_IN + 5], 0.f);
    __syncthreads();
    for (int d = 1; d < LL; d <<= 1) {
        float add = (j >= d) ? s[j - d] : 0.f;
        __syncthreads();
        s[j] += add;
        __syncthreads();
    }
    ts[b * LL + j] = s[j];
}

// ---------------- h0 = (hist @ Wp + bp) * vm ----------------
__global__ __launch_bounds__(256) void k_h0(const float* __restrict__ hist, const float* __restrict__ mask,
                                            const float* __restrict__ Wp, const float* __restrict__ bp,
                                            float* __restrict__ h) {
    int idx = blockIdx.x * 256 + threadIdx.x;
    if (idx >= BB * LL * HH) return;
    int k = idx & (HH - 1);
    int bi = idx >> 7;
    const float* hr = hist + (size_t)bi * D_IN;
    float acc = bp[k];
#pragma unroll
    for (int f = 0; f < D_IN; f++) acc += hr[f] * Wp[f * HH + k];
    float vm = mask[bi] > 0.f ? 1.f : 0.f;
    h[idx] = acc * vm;
}

// ---------------- composed matrices, transposed bf16: AmT[c][r] = (We2@WaE)[r][c] ----------------
__global__ __launch_bounds__(HH) void k_compose(const float* __restrict__ We2, const float* __restrict__ be2,
                                                const float* __restrict__ Wa1, const float* __restrict__ ba1,
                                                const float* __restrict__ Wm1, const float* __restrict__ bm1,
                                                short* __restrict__ AmT, short* __restrict__ MmT,
                                                float* __restrict__ ca, float* __restrict__ cm, int l) {
    int p = blockIdx.x, q = threadIdx.x;
    __shared__ float row[HH];
    const float* WaE = Wa1 + (size_t)(l * 3 * HH + 2 * HH) * HH;
    const float* WmE = Wm1 + (size_t)(l * 2 * HH + HH) * HH;
    if (p < HH) {
        row[q] = We2[(size_t)(l * HH + p) * HH + q];
        __syncthreads();
        float a = 0.f, m = 0.f;
        for (int k = 0; k < HH; k++) { float w = row[k]; a += w * WaE[k * HH + q]; m += w * WmE[k * HH + q]; }
        AmT[q * HH + p] = f2bf(a);
        MmT[q * HH + p] = f2bf(m);
    } else {
        row[q] = be2[l * HH + q];
        __syncthreads();
        float a = 0.f, m = 0.f;
        for (int k = 0; k < HH; k++) { float w = row[k]; a += w * WaE[k * HH + q]; m += w * WmE[k * HH + q]; }
        ca[q] = a + ba1[l * HH + q];
        cm[q] = m + bm1[l * HH + q];
    }
}

// ---------------- per-(b,i) projections: sa, da, ma, oa ----------------
__global__ __launch_bounds__(256) void k_pre(const float* __restrict__ h, const float* __restrict__ Wa1,
                                             const float* __restrict__ Wm1, const float* __restrict__ Wo1,
                                             float* __restrict__ sa, float* __restrict__ da,
                                             float* __restrict__ ma, float* __restrict__ oa, int l) {
    int bi = blockIdx.x, tid = threadIdx.x;
    __shared__ float hs[HH];
    if (tid < HH) hs[tid] = h[(size_t)bi * HH + tid];
    __syncthreads();
    for (int o = tid; o < 4 * HH; o += 256) {
        int m = o >> 7, k = o & (HH - 1);
        const float* W;
        float* dst;
        if (m == 0)      { W = Wa1 + (size_t)(l * 3 * HH) * HH;        dst = sa; }
        else if (m == 1) { W = Wa1 + (size_t)(l * 3 * HH + HH) * HH;   dst = da; }
        else if (m == 2) { W = Wm1 + (size_t)(l * 2 * HH) * HH;        dst = ma; }
        else             { W = Wo1 + (size_t)(l * 2 * HH) * HH;        dst = oa; }
        float acc = 0.f;
        for (int kk = 0; kk < HH; kk++) acc += hs[kk] * W[kk * HH + k];
        dst[(size_t)bi * HH + k] = acc;
    }
}

// ---------------- main fused attention/message kernel (MFMA): one block per (b,i) ----------------
__global__ __launch_bounds__(256) void k_attn(
    const float* __restrict__ hist, const float* __restrict__ mask, const float* __restrict__ ts,
    const float* __restrict__ sa, const float* __restrict__ da, const float* __restrict__ ma,
    const short* __restrict__ AmT, const short* __restrict__ MmT,
    const float* __restrict__ ca, const float* __restrict__ cm,
    const float* __restrict__ wa2, const float* __restrict__ ba2,
    const float* __restrict__ Wm2, const float* __restrict__ bm2,
    const float* __restrict__ We1, const float* __restrict__ be1,
    float* __restrict__ agg, int l) {
    __shared__ __align__(16) short t_lds[LL][136];
    __shared__ float We1_s[512], be1_s[LL];
    __shared__ float efa_s[LL], efb_s[LL], efc_s[LL], efd_s[LL];
    __shared__ float lat_s[LL], lon_s[LL], src_s[LL], tss_s[LL], val_s[LL];
    __shared__ float base_a_s[LL], base_m_s[LL], wa2_s[LL];
    __shared__ float w_s[LL], att4[4 * LL], v_s[LL], red_s[8];

    const int tid = threadIdx.x;
    const int lane = tid & 63;
    const int wv = tid >> 6;
    const int lo = lane & 15, g4 = lane >> 4;
    const int bi = blockIdx.x, b = bi >> 7, i = bi & (LL - 1);

    // --- B1 fragments (Amat^T, bf16) from global: issue early, L2-resident ---
    bf16x8 Bf[2][4];
#pragma unroll
    for (int ct = 0; ct < 2; ct++) {
        int col = wv * 32 + ct * 16 + lo;
#pragma unroll
        for (int ks = 0; ks < 4; ks++)
            Bf[ct][ks] = *(const bf16x8*)(AmT + col * HH + ks * 32 + g4 * 8);
    }

    // --- stage small arrays ---
    const float* We1l = We1 + l * 4 * HH;
    We1_s[tid] = We1l[tid];
    We1_s[tid + 256] = We1l[tid + 256];
    if (tid < LL) {
        int bj = b * LL + tid;
        lat_s[tid] = hist[(size_t)bj * D_IN + 0];
        lon_s[tid] = hist[(size_t)bj * D_IN + 1];
        src_s[tid] = hist[(size_t)bj * D_IN + 6];
        tss_s[tid] = ts[bj];
        val_s[tid] = mask[bj];
        be1_s[tid] = be1[l * HH + tid];
        base_a_s[tid] = sa[(size_t)bi * HH + tid] + ca[tid];
        base_m_s[tid] = ma[(size_t)bi * HH + tid] + cm[tid];
        wa2_s[tid] = wa2[l * HH + tid];
    }
    __syncthreads();
    if (tid < LL) {
        float dlat = lat_s[i] - lat_s[tid], dlon = lon_s[i] - lon_s[tid];
        efa_s[tid] = sqrtf(dlat * dlat + dlon * dlon + 1e-8f);
        efb_s[tid] = fabsf(tss_s[i] - tss_s[tid]) * (1.f / 300.f);
        efc_s[tid] = (src_s[i] == src_s[tid]) ? 1.f : 0.f;
        efd_s[tid] = (tid == i) ? 1.f : 0.f;
    }
    __syncthreads();

    // --- acc init: base_a[k] + da[j][k] folded into C (loads hide under t-compute) ---
    f32x4 acc[8][2];
    const float* da_b = da + (size_t)(b * LL) * HH;
#pragma unroll
    for (int jt = 0; jt < 8; jt++)
#pragma unroll
        for (int ct = 0; ct < 2; ct++)
#pragma unroll
            for (int rg = 0; rg < 4; rg++) {
                int j = jt * 16 + g4 * 4 + rg;
                int k = wv * 32 + ct * 16 + lo;
                acc[jt][ct][rg] = base_a_s[k] + da_b[(size_t)j * HH + k];
            }

    // --- t = relu(ef @ We1 + be1) -> LDS bf16, computed ONCE ---
    {
        int jj = tid & (LL - 1);
        float ea = efa_s[jj], eb = efb_s[jj], ec = efc_s[jj], ed = efd_s[jj];
#pragma unroll
        for (int pass = 0; pass < 8; pass++) {
            int r0 = ((tid >> 7) + pass * 2) * 8;
            short8v pk;
#pragma unroll
            for (int e = 0; e < 8; e++) {
                int r = r0 + e;
                float v = ea * We1_s[r] + eb * We1_s[128 + r] + ec * We1_s[256 + r] + ed * We1_s[384 + r] + be1_s[r];
                pk[e] = f2bf(fmaxf(v, 0.f));
            }
            *(short8v*)&t_lds[jj][r0] = pk;
        }
    }
    __syncthreads();

    // --- GEMM1: U_a = t @ Amat (wave wv owns cols [32wv, 32wv+32)) ---
#pragma unroll
    for (int ks = 0; ks < 4; ks++) {
        bf16x8 tf[8];
#pragma unroll
        for (int jt = 0; jt < 8; jt++)
            tf[jt] = *(const bf16x8*)&t_lds[jt * 16 + lo][ks * 32 + g4 * 8];
#pragma unroll
        for (int jt = 0; jt < 8; jt++) {
            acc[jt][0] = MFMA_B16(tf[jt], Bf[0][ks], acc[jt][0]);
            acc[jt][1] = MFMA_B16(tf[jt], Bf[1][ks], acc[jt][1]);
        }
    }

    // --- preload B2 fragments (Mmat^T) to hide under tanh section ---
#pragma unroll
    for (int ct = 0; ct < 2; ct++) {
        int col = wv * 32 + ct * 16 + lo;
#pragma unroll
        for (int ks = 0; ks < 4; ks++)
            Bf[ct][ks] = *(const bf16x8*)(MmT + col * HH + ks * 32 + g4 * 8);
    }

    // --- att partials: sum_k tanh(acc)·wa2[k]; butterfly over lo ---
    {
        int k0 = wv * 32 + lo, k1 = k0 + 16;
        float w0 = wa2_s[k0], w1 = wa2_s[k1];
#pragma unroll
        for (int jt = 0; jt < 8; jt++) {
#pragma unroll
            for (int rg = 0; rg < 4; rg++) {
                float p = tanh_fast(acc[jt][0][rg]) * w0 + tanh_fast(acc[jt][1][rg]) * w1;
                p += __shfl_xor(p, 1);
                p += __shfl_xor(p, 2);
                p += __shfl_xor(p, 4);
                p += __shfl_xor(p, 8);
                if (lo == 0) att4[wv * LL + jt * 16 + g4 * 4 + rg] = p;
            }
        }
    }
    __syncthreads();

    // --- softmax over j (2 waves handle 128 rows) ---
    const float inv = 0.08838834764831845f;  // 1/sqrt(128)
    float ba2l = ba2[l];
    float av = 0.f, ev = 0.f;
    if (tid < LL) {
        float a = (att4[tid] + att4[LL + tid] + att4[2 * LL + tid] + att4[3 * LL + tid] + ba2l) * inv;
        if (!(val_s[tid] > 0.f) || !(val_s[i] > 0.f)) a = -1e9f;
        av = a;
        float m = a;
#pragma unroll
        for (int d = 1; d < 64; d <<= 1) m = fmaxf(m, __shfl_xor(m, d));
        if ((tid & 63) == 0) red_s[tid >> 6] = m;
    }
    __syncthreads();
    float mx = fmaxf(red_s[0], red_s[1]);
    if (tid < LL) {
        ev = __expf(av - mx);
        float s = ev;
#pragma unroll
        for (int d = 1; d < 64; d <<= 1) s += __shfl_xor(s, d);
        if ((tid & 63) == 0) red_s[4 + (tid >> 6)] = s;
    }
    __syncthreads();
    if (tid < LL) w_s[tid] = ev / (red_s[4] + red_s[5]);
    __syncthreads();

    // --- GEMM2: U_m = t @ Mmat, acc init = base_m[k] ---
#pragma unroll
    for (int jt = 0; jt < 8; jt++)
#pragma unroll
        for (int ct = 0; ct < 2; ct++) {
            int k = wv * 32 + ct * 16 + lo;
            float bm = base_m_s[k];
#pragma unroll
            for (int rg = 0; rg < 4; rg++) acc[jt][ct][rg] = bm;
        }
#pragma unroll
    for (int ks = 0; ks < 4; ks++) {
        bf16x8 tf[8];
#pragma unroll
        for (int jt = 0; jt < 8; jt++)
            tf[jt] = *(const bf16x8*)&t_lds[jt * 16 + lo][ks * 32 + g4 * 8];
#pragma unroll
        for (int jt = 0; jt < 8; jt++) {
            acc[jt][0] = MFMA_B16(tf[jt], Bf[0][ks], acc[jt][0]);
            acc[jt][1] = MFMA_B16(tf[jt], Bf[1][ks], acc[jt][1]);
        }
    }

    // --- weighted relu-msg sum over j ---
    {
        float mac0 = 0.f, mac1 = 0.f;
#pragma unroll
        for (int jt = 0; jt < 8; jt++)
#pragma unroll
            for (int rg = 0; rg < 4; rg++) {
                float wj = w_s[jt * 16 + g4 * 4 + rg];
                mac0 += wj * fmaxf(acc[jt][0][rg], 0.f);
                mac1 += wj * fmaxf(acc[jt][1][rg], 0.f);
            }
        mac0 += __shfl_xor(mac0, 16);
        mac0 += __shfl_xor(mac0, 32);
        mac1 += __shfl_xor(mac1, 16);
        mac1 += __shfl_xor(mac1, 32);
        if (g4 == 0) {
            v_s[wv * 32 + lo] = mac0;
            v_s[wv * 32 + 16 + lo] = mac1;
        }
    }
    __syncthreads();

    // --- agg = v @ Wm2 + bm2 ---
    if (tid < LL) {
        const float* Wm2l = Wm2 + (size_t)l * HH * HH;
        float a = bm2[l * HH + tid];
#pragma unroll 8
        for (int kk = 0; kk < HH; kk++) a += v_s[kk] * Wm2l[kk * HH + tid];
        agg[(size_t)bi * HH + tid] = a;
    }
}

// ---------------- out MLP + residual + LayerNorm ----------------
__global__ __launch_bounds__(HH) void k_post(const float* __restrict__ h, const float* __restrict__ oa,
                                             const float* __restrict__ agg, const float* __restrict__ mask,
                                             const float* __restrict__ Wo1, const float* __restrict__ bo1,
                                             const float* __restrict__ Wo2, const float* __restrict__ bo2,
                                             const float* __restrict__ ln_g, const float* __restrict__ ln_b,
                                             float* __restrict__ hout, int l) {
    int bi = blockIdx.x, k = threadIdx.x;
    __shared__ float ag_s[HH], g_s[HH], hs[HH], red[HH];
    ag_s[k] = agg[(size_t)bi * HH + k];
    hs[k] = h[(size_t)bi * HH + k];
    __syncthreads();
    const float* W1 = Wo1 + (size_t)(l * 2 * HH + HH) * HH;
    float x1 = oa[(size_t)bi * HH + k] + bo1[l * HH + k];
    for (int kk = 0; kk < HH; kk++) x1 += ag_s[kk] * W1[kk * HH + k];
    g_s[k] = fmaxf(x1, 0.f);
    __syncthreads();
    const float* W2 = Wo2 + (size_t)l * HH * HH;
    float o = bo2[l * HH + k];
    for (int kk = 0; kk < HH; kk++) o += g_s[kk] * W2[kk * HH + k];
    float y = hs[k] + o;
    red[k] = y;
    __syncthreads();
    for (int s = 64; s > 0; s >>= 1) { if (k < s) red[k] += red[k + s]; __syncthreads(); }
    float mu = red[0] / HH;
    __syncthreads();
    float d = y - mu;
    red[k] = d * d;
    __syncthreads();
    for (int s = 64; s > 0; s >>= 1) { if (k < s) red[k] += red[k + s]; __syncthreads(); }
    float var = red[0] / HH;
    float vm = mask[bi] > 0.f ? 1.f : 0.f;
    hout[(size_t)bi * HH + k] = ((y - mu) * rsqrtf(var + 1e-5f) * ln_g[l * HH + k] + ln_b[l * HH + k]) * vm;
}

// ---------------- decoder ----------------
__global__ __launch_bounds__(HH) void k_dec(const float* __restrict__ hist, const float* __restrict__ mask,
                                            const float* __restrict__ h, const float* __restrict__ hg,
                                            const float* __restrict__ hb, const float* __restrict__ Wh1,
                                            const float* __restrict__ bh1, const float* __restrict__ Wh2,
                                            const float* __restrict__ bh2, float* __restrict__ out) {
    int b = blockIdx.x, t = threadIdx.x;
    const int N = D_IN + HH;  // 136
    __shared__ float red[HH], x_s[D_IN + HH], u_s[HH];
    red[t] = mask[b * LL + t];
    __syncthreads();
    for (int s = 64; s > 0; s >>= 1) { if (t < s) red[t] += red[t + s]; __syncthreads(); }
    int vc = (int)red[0];
    vc = min(max(vc, 1), LL);
    int last = vc - 1;
    __syncthreads();
    if (t < D_IN) x_s[t] = hist[(size_t)(b * LL + last) * D_IN + t];
    x_s[D_IN + t] = h[(size_t)(b * LL + last) * HH + t];
    __syncthreads();
    float ps = 0.f;
    for (int f = t; f < N; f += HH) ps += x_s[f];
    red[t] = ps;
    __syncthreads();
    for (int s = 64; s > 0; s >>= 1) { if (t < s) red[t] += red[t + s]; __syncthreads(); }
    float mu = red[0] / N;
    __syncthreads();
    ps = 0.f;
    for (int f = t; f < N; f += HH) { float d = x_s[f] - mu; ps += d * d; }
    red[t] = ps;
    __syncthreads();
    for (int s = 64; s > 0; s >>= 1) { if (t < s) red[t] += red[t + s]; __syncthreads(); }
    float var = red[0] / N;
    float rs = rsqrtf(var + 1e-5f);
    __syncthreads();
    for (int f = t; f < N; f += HH) x_s[f] = (x_s[f] - mu) * rs * hg[f] + hb[f];
    __syncthreads();
    float acc = bh1[t];
    for (int f = 0; f < N; f++) acc += x_s[f] * Wh1[f * HH + t];
    u_s[t] = fmaxf(acc, 0.f);
    __syncthreads();
    if (t < FUT * MDIM) {
        float o = bh2[t];
        for (int k = 0; k < HH; k++) o += u_s[k] * Wh2[k * FUT * MDIM + t];
        if (isnan(o)) o = 0.f;
        else if (isinf(o)) o = (o > 0.f) ? 1e4f : -1e4f;
        out[b * FUT * MDIM + t] = o;
    }
}

// ---------------- copy h to output ----------------
__global__ __launch_bounds__(256) void k_copy(const float* __restrict__ h, float* __restrict__ out) {
    int idx = blockIdx.x * 256 + threadIdx.x;
    if (idx < BB * LL * HH) out[BB * FUT * MDIM + idx] = h[idx];
}

extern "C" void kernel_launch(void* const* d_in, const int* in_sizes, int n_in,
                              void* d_out, int out_size, void* d_ws, size_t ws_size,
                              hipStream_t stream) {
    const float* hist = (const float*)d_in[0];
    const float* mask = (const float*)d_in[1];
    const float* Wp  = (const float*)d_in[2];
    const float* bp  = (const float*)d_in[3];
    const float* We1 = (const float*)d_in[4];
    const float* be1 = (const float*)d_in[5];
    const float* We2 = (const float*)d_in[6];
    const float* be2 = (const float*)d_in[7];
    const float* Wa1 = (const float*)d_in[8];
    const float* ba1 = (const float*)d_in[9];
    const float* wa2 = (const float*)d_in[10];
    const float* ba2 = (const float*)d_in[11];
    const float* Wm1 = (const float*)d_in[12];
    const float* bm1 = (const float*)d_in[13];
    const float* Wm2 = (const float*)d_in[14];
    const float* bm2 = (const float*)d_in[15];
    const float* Wo1 = (const float*)d_in[16];
    const float* bo1 = (const float*)d_in[17];
    const float* Wo2 = (const float*)d_in[18];
    const float* bo2 = (const float*)d_in[19];
    const float* ln_g = (const float*)d_in[20];
    const float* ln_b = (const float*)d_in[21];
    const float* hg  = (const float*)d_in[22];
    const float* hb  = (const float*)d_in[23];
    const float* Wh1 = (const float*)d_in[24];
    const float* bh1 = (const float*)d_in[25];
    const float* Wh2 = (const float*)d_in[26];
    const float* bh2 = (const float*)d_in[27];
    float* out = (float*)d_out;

    float* ws = (float*)d_ws;
    float* ts_w  = ws; ws += BB * LL;
    float* h_w   = ws; ws += BB * LL * HH;
    float* sa_w  = ws; ws += BB * LL * HH;
    float* da_w  = ws; ws += BB * LL * HH;
    float* ma_w  = ws; ws += BB * LL * HH;
    float* oa_w  = ws; ws += BB * LL * HH;
    float* agg_w = ws; ws += BB * LL * HH;
    short* AmT_w = (short*)ws; ws += HH * HH / 2;
    short* MmT_w = (short*)ws; ws += HH * HH / 2;
    float* ca_w  = ws; ws += HH;
    float* cm_w  = ws; ws += HH;

    k_ts<<<BB, LL, 0, stream>>>(hist, ts_w);
    k_h0<<<(BB * LL * HH + 255) / 256, 256, 0, stream>>>(hist, mask, Wp, bp, h_w);
    for (int l = 0; l < NLAYER; l++) {
        k_compose<<<HH + 1, HH, 0, stream>>>(We2, be2, Wa1, ba1, Wm1, bm1, AmT_w, MmT_w, ca_w, cm_w, l);
        k_pre<<<BB * LL, 256, 0, stream>>>(h_w, Wa1, Wm1, Wo1, sa_w, da_w, ma_w, oa_w, l);
        k_attn<<<BB * LL, 256, 0, stream>>>(hist, mask, ts_w, sa_w, da_w, ma_w, AmT_w, MmT_w, ca_w, cm_w,
                                            wa2, ba2, Wm2, bm2, We1, be1, agg_w, l);
        k_post<<<BB * LL, HH, 0, stream>>>(h_w, oa_w, agg_w, mask, Wo1, bo1, Wo2, bo2, ln_g, ln_b, h_w, l);
    }
    k_dec<<<BB, HH, 0, stream>>>(hist, mask, h_w, hg, hb, Wh1, bh1, Wh2, bh2, out);
    k_copy<<<(BB * LL * HH + 255) / 256, 256, 0, stream>>>(h_w, out);
}

// Round 3
// 318.798 us; speedup vs baseline: 5.2733x; 1.5023x over previous
//
#include <hip/hip_runtime.h>
#include <math.h>

#define BB 16
#define LL 128
#define D_IN 8
#define HH 128
#define NLAYER 2
#define FUT 12
#define MDIM 2

typedef __attribute__((ext_vector_type(8))) __bf16 bf16x8;
typedef __attribute__((ext_vector_type(8))) short short8v;
typedef __attribute__((ext_vector_type(4))) float f32x4;

#define MFMA_B16(A, B, C) __builtin_amdgcn_mfma_f32_16x16x32_bf16(A, B, C, 0, 0, 0)

static __device__ __forceinline__ short f2bf(float f) {
    union { float f; unsigned u; } v; v.f = f;
    unsigned r = v.u + 0x7FFFu + ((v.u >> 16) & 1u);
    return (short)(r >> 16);
}

static __device__ __forceinline__ float tanh_fast(float x) {
    float e = __expf(2.f * x);
    return 1.f - 2.f / (e + 1.f);
}

// ---------------- ts cumsum (inclusive) ----------------
__global__ __launch_bounds__(LL) void k_ts(const float* __restrict__ hist, float* __restrict__ ts) {
    int b = blockIdx.x, j = threadIdx.x;
    __shared__ float s[LL];
    s[j] = fmaxf(hist[(b * LL + j) * D_IN + 5], 0.f);
    __syncthreads();
    for (int d = 1; d < LL; d <<= 1) {
        float add = (j >= d) ? s[j - d] : 0.f;
        __syncthreads();
        s[j] += add;
        __syncthreads();
    }
    ts[b * LL + j] = s[j];
}

// ---------------- h0 = (hist @ Wp + bp) * vm ----------------
__global__ __launch_bounds__(256) void k_h0(const float* __restrict__ hist, const float* __restrict__ mask,
                                            const float* __restrict__ Wp, const float* __restrict__ bp,
                                            float* __restrict__ h) {
    int idx = blockIdx.x * 256 + threadIdx.x;
    if (idx >= BB * LL * HH) return;
    int k = idx & (HH - 1);
    int bi = idx >> 7;
    const float* hr = hist + (size_t)bi * D_IN;
    float acc = bp[k];
#pragma unroll
    for (int f = 0; f < D_IN; f++) acc += hr[f] * Wp[f * HH + k];
    float vm = mask[bi] > 0.f ? 1.f : 0.f;
    h[idx] = acc * vm;
}

// ---------------- composed matrices for BOTH layers, transposed bf16 ----------------
__global__ __launch_bounds__(HH) void k_compose(const float* __restrict__ We2, const float* __restrict__ be2,
                                                const float* __restrict__ Wa1, const float* __restrict__ ba1,
                                                const float* __restrict__ Wm1, const float* __restrict__ bm1,
                                                short* __restrict__ AmT, short* __restrict__ MmT,
                                                float* __restrict__ ca, float* __restrict__ cm) {
    int blk = blockIdx.x;
    int l = blk / (HH + 1);
    int p = blk % (HH + 1);
    int q = threadIdx.x;
    __shared__ float row[HH];
    const float* WaE = Wa1 + (size_t)(l * 3 * HH + 2 * HH) * HH;
    const float* WmE = Wm1 + (size_t)(l * 2 * HH + HH) * HH;
    if (p < HH) {
        row[q] = We2[(size_t)(l * HH + p) * HH + q];
        __syncthreads();
        float a = 0.f, m = 0.f;
        for (int k = 0; k < HH; k++) { float w = row[k]; a += w * WaE[k * HH + q]; m += w * WmE[k * HH + q]; }
        AmT[(size_t)l * HH * HH + q * HH + p] = f2bf(a);
        MmT[(size_t)l * HH * HH + q * HH + p] = f2bf(m);
    } else {
        row[q] = be2[l * HH + q];
        __syncthreads();
        float a = 0.f, m = 0.f;
        for (int k = 0; k < HH; k++) { float w = row[k]; a += w * WaE[k * HH + q]; m += w * WmE[k * HH + q]; }
        ca[l * HH + q] = a + ba1[l * HH + q];
        cm[l * HH + q] = m + bm1[l * HH + q];
    }
}

// ---------------- da only: da[bj][k] = h[bj] @ Wa1[l, H:2H] ----------------
__global__ __launch_bounds__(HH) void k_da(const float* __restrict__ h, const float* __restrict__ Wa1,
                                           float* __restrict__ da, int l) {
    int bi = blockIdx.x, t = threadIdx.x;
    __shared__ float hs[HH];
    hs[t] = h[(size_t)bi * HH + t];
    __syncthreads();
    const float* W = Wa1 + (size_t)(l * 3 * HH + HH) * HH;
    float a0 = 0.f, a1 = 0.f, a2 = 0.f, a3 = 0.f;
#pragma unroll 8
    for (int kk = 0; kk < 32; kk++) {
        a0 += hs[kk] * W[kk * HH + t];
        a1 += hs[kk + 32] * W[(kk + 32) * HH + t];
        a2 += hs[kk + 64] * W[(kk + 64) * HH + t];
        a3 += hs[kk + 96] * W[(kk + 96) * HH + t];
    }
    da[(size_t)bi * HH + t] = (a0 + a1) + (a2 + a3);
}

// ---------------- fused attention + message + out-MLP + LN: one block per (b,i) ----------------
__global__ __launch_bounds__(256, 4) void k_attn(
    const float* __restrict__ hist, const float* __restrict__ mask, const float* __restrict__ ts,
    const float* __restrict__ h, const float* __restrict__ da,
    const short* __restrict__ AmT, const short* __restrict__ MmT,
    const float* __restrict__ ca, const float* __restrict__ cm,
    const float* __restrict__ Wa1, const float* __restrict__ Wm1,
    const float* __restrict__ wa2, const float* __restrict__ ba2,
    const float* __restrict__ Wm2, const float* __restrict__ bm2,
    const float* __restrict__ We1, const float* __restrict__ be1,
    const float* __restrict__ Wo1, const float* __restrict__ bo1,
    const float* __restrict__ Wo2, const float* __restrict__ bo2,
    const float* __restrict__ ln_g, const float* __restrict__ ln_b,
    float* __restrict__ hout, float* __restrict__ hcopy, int l) {
    __shared__ __align__(16) short t_lds[LL][136];   // 34816 B
    __shared__ float bufA[512];                      // We1 staging -> att4 -> {agg, oa, g}
    __shared__ float bufB[128];                      // be1 staging -> LN reductions
    __shared__ float v_s[128];
    __shared__ float val_s[128], base_a[128], base_m[128], wa2_s[128], h_i[128];

    const int tid = threadIdx.x;
    const int lane = tid & 63;
    const int wv = tid >> 6;
    const int lo = lane & 15, g4 = lane >> 4;
    const int bi = blockIdx.x, b = bi >> 7, i = bi & (LL - 1);

    // --- B1 fragments (Amat^T bf16), issue early (L2) ---
    bf16x8 Bf[2][4];
#pragma unroll
    for (int ct = 0; ct < 2; ct++) {
        int col = wv * 32 + ct * 16 + lo;
#pragma unroll
        for (int ks = 0; ks < 4; ks++)
            Bf[ct][ks] = *(const bf16x8*)(AmT + (size_t)l * HH * HH + col * HH + ks * 32 + g4 * 8);
    }

    // --- stage ---
    const float* We1l = We1 + l * 4 * HH;
    bufA[tid] = We1l[tid];
    bufA[tid + 256] = We1l[tid + 256];
    if (tid < LL) {
        h_i[tid] = h[(size_t)bi * HH + tid];
        val_s[tid] = mask[b * LL + tid];
        wa2_s[tid] = wa2[l * HH + tid];
        bufB[tid] = be1[l * HH + tid];
    }
    __syncthreads();

    // --- in-block sa/ma GEMVs -> base_a/base_m (results used after next barrier) ---
    {
        int k = tid & (HH - 1);
        const float* W = (tid < LL) ? (Wa1 + (size_t)(l * 3 * HH) * HH) : (Wm1 + (size_t)(l * 2 * HH) * HH);
        float a0 = 0.f, a1 = 0.f, a2 = 0.f, a3 = 0.f;
#pragma unroll 8
        for (int kk = 0; kk < 32; kk++) {
            a0 += h_i[kk] * W[kk * HH + k];
            a1 += h_i[kk + 32] * W[(kk + 32) * HH + k];
            a2 += h_i[kk + 64] * W[(kk + 64) * HH + k];
            a3 += h_i[kk + 96] * W[(kk + 96) * HH + k];
        }
        float r = (a0 + a1) + (a2 + a3);
        if (tid < LL) base_a[k] = r + ca[l * HH + k];
        else          base_m[k] = r + cm[l * HH + k];
    }

    // --- per-thread edge features + t = relu(ef @ We1 + be1) -> LDS bf16 ---
    {
        int jj = tid & (LL - 1);
        const float* hri = hist + (size_t)(b * LL + i) * D_IN;
        const float* hrj = hist + (size_t)(b * LL + jj) * D_IN;
        float dlat = hri[0] - hrj[0], dlon = hri[1] - hrj[1];
        float ea = sqrtf(dlat * dlat + dlon * dlon + 1e-8f);
        float eb = fabsf(ts[b * LL + i] - ts[b * LL + jj]) * (1.f / 300.f);
        float ec = (hri[6] == hrj[6]) ? 1.f : 0.f;
        float ed = (jj == i) ? 1.f : 0.f;
#pragma unroll
        for (int pass = 0; pass < 8; pass++) {
            int r0 = ((tid >> 7) + pass * 2) * 8;
            short8v pk;
#pragma unroll
            for (int e = 0; e < 8; e++) {
                int r = r0 + e;
                float v = ea * bufA[r] + eb * bufA[128 + r] + ec * bufA[256 + r] + ed * bufA[384 + r] + bufB[r];
                pk[e] = f2bf(fmaxf(v, 0.f));
            }
            *(short8v*)&t_lds[jj][r0] = pk;
        }
    }

    // --- acc init from da (tanh adds base_a later) ---
    f32x4 acc[8][2];
    const float* da_b = da + (size_t)(b * LL) * HH;
#pragma unroll
    for (int jt = 0; jt < 8; jt++)
#pragma unroll
        for (int ct = 0; ct < 2; ct++)
#pragma unroll
            for (int rg = 0; rg < 4; rg++)
                acc[jt][ct][rg] = da_b[(size_t)(jt * 16 + g4 * 4 + rg) * HH + wv * 32 + ct * 16 + lo];
    __syncthreads();

    // --- GEMM1: U_a = t @ Amat ---
#pragma unroll
    for (int ks = 0; ks < 4; ks++) {
#pragma unroll
        for (int jh = 0; jh < 2; jh++) {
            bf16x8 tf[4];
#pragma unroll
            for (int m = 0; m < 4; m++)
                tf[m] = *(const bf16x8*)&t_lds[(jh * 4 + m) * 16 + lo][ks * 32 + g4 * 8];
#pragma unroll
            for (int m = 0; m < 4; m++) {
                acc[jh * 4 + m][0] = MFMA_B16(tf[m], Bf[0][ks], acc[jh * 4 + m][0]);
                acc[jh * 4 + m][1] = MFMA_B16(tf[m], Bf[1][ks], acc[jh * 4 + m][1]);
            }
        }
    }

    // --- preload B2 (Mmat^T) ---
#pragma unroll
    for (int ct = 0; ct < 2; ct++) {
        int col = wv * 32 + ct * 16 + lo;
#pragma unroll
        for (int ks = 0; ks < 4; ks++)
            Bf[ct][ks] = *(const bf16x8*)(MmT + (size_t)l * HH * HH + col * HH + ks * 32 + g4 * 8);
    }

    // --- tanh + att partials -> bufA (att4) ---
    {
        int k0 = wv * 32 + lo, k1 = k0 + 16;
        float ba0 = base_a[k0], ba1v = base_a[k1];
        float w0a = wa2_s[k0], w1a = wa2_s[k1];
#pragma unroll
        for (int jt = 0; jt < 8; jt++) {
#pragma unroll
            for (int rg = 0; rg < 4; rg++) {
                float p = tanh_fast(acc[jt][0][rg] + ba0) * w0a + tanh_fast(acc[jt][1][rg] + ba1v) * w1a;
                p += __shfl_xor(p, 1);
                p += __shfl_xor(p, 2);
                p += __shfl_xor(p, 4);
                p += __shfl_xor(p, 8);
                if (lo == 0) bufA[wv * LL + jt * 16 + g4 * 4 + rg] = p;
            }
        }
    }
    __syncthreads();

    // --- redundant per-wave softmax (no extra barriers) ---
    float w0, w1;
    {
        const float inv = 0.08838834764831845f;  // 1/sqrt(128)
        float ba2l = ba2[l];
        float vi = val_s[i];
        float a0 = (bufA[lane] + bufA[128 + lane] + bufA[256 + lane] + bufA[384 + lane] + ba2l) * inv;
        float a1 = (bufA[64 + lane] + bufA[192 + lane] + bufA[320 + lane] + bufA[448 + lane] + ba2l) * inv;
        if (!(val_s[lane] > 0.f) || !(vi > 0.f)) a0 = -1e9f;
        if (!(val_s[64 + lane] > 0.f) || !(vi > 0.f)) a1 = -1e9f;
        float m = fmaxf(a0, a1);
#pragma unroll
        for (int d = 1; d < 64; d <<= 1) m = fmaxf(m, __shfl_xor(m, d));
        float e0 = __expf(a0 - m), e1 = __expf(a1 - m);
        float s = e0 + e1;
#pragma unroll
        for (int d = 1; d < 64; d <<= 1) s += __shfl_xor(s, d);
        float rs = 1.f / s;
        w0 = e0 * rs;
        w1 = e1 * rs;
    }

    // --- GEMM2: U_m = t @ Mmat (acc reinit 0) ---
#pragma unroll
    for (int jt = 0; jt < 8; jt++)
#pragma unroll
        for (int ct = 0; ct < 2; ct++)
#pragma unroll
            for (int rg = 0; rg < 4; rg++) acc[jt][ct][rg] = 0.f;
#pragma unroll
    for (int ks = 0; ks < 4; ks++) {
#pragma unroll
        for (int jh = 0; jh < 2; jh++) {
            bf16x8 tf[4];
#pragma unroll
            for (int m = 0; m < 4; m++)
                tf[m] = *(const bf16x8*)&t_lds[(jh * 4 + m) * 16 + lo][ks * 32 + g4 * 8];
#pragma unroll
            for (int m = 0; m < 4; m++) {
                acc[jh * 4 + m][0] = MFMA_B16(tf[m], Bf[0][ks], acc[jh * 4 + m][0]);
                acc[jh * 4 + m][1] = MFMA_B16(tf[m], Bf[1][ks], acc[jh * 4 + m][1]);
            }
        }
    }

    // --- weighted relu-msg sum over j (w via shfl) ---
    {
        int k0 = wv * 32 + lo;
        float bm0 = base_m[k0], bm1v = base_m[k0 + 16];
        float mac0 = 0.f, mac1 = 0.f;
#pragma unroll
        for (int jt = 0; jt < 8; jt++) {
#pragma unroll
            for (int rg = 0; rg < 4; rg++) {
                int j = jt * 16 + g4 * 4 + rg;
                float wj = (jt < 4) ? __shfl(w0, j) : __shfl(w1, j - 64);
                mac0 += wj * fmaxf(acc[jt][0][rg] + bm0, 0.f);
                mac1 += wj * fmaxf(acc[jt][1][rg] + bm1v, 0.f);
            }
        }
        mac0 += __shfl_xor(mac0, 16);
        mac0 += __shfl_xor(mac0, 32);
        mac1 += __shfl_xor(mac1, 16);
        mac1 += __shfl_xor(mac1, 32);
        if (g4 == 0) {
            v_s[wv * 32 + lo] = mac0;
            v_s[wv * 32 + 16 + lo] = mac1;
        }
    }
    __syncthreads();

    // --- post: agg GEMV (tid<128) || oa GEMV (tid>=128), into bufA ---
    {
        int k = tid & (HH - 1);
        const float* x = (tid < LL) ? v_s : h_i;
        const float* W = (tid < LL) ? (Wm2 + (size_t)l * HH * HH) : (Wo1 + (size_t)(l * 2 * HH) * HH);
        float a0 = 0.f, a1 = 0.f, a2 = 0.f, a3 = 0.f;
#pragma unroll 8
        for (int kk = 0; kk < 32; kk++) {
            a0 += x[kk] * W[kk * HH + k];
            a1 += x[kk + 32] * W[(kk + 32) * HH + k];
            a2 += x[kk + 64] * W[(kk + 64) * HH + k];
            a3 += x[kk + 96] * W[(kk + 96) * HH + k];
        }
        float r = (a0 + a1) + (a2 + a3);
        if (tid < LL) bufA[k] = r + bm2[l * HH + k];   // agg
        else          bufA[128 + k] = r;               // oa
    }
    __syncthreads();

    // --- x1 = relu(oa + agg @ Wo1[H:] + bo1) -> g ---
    if (tid < LL) {
        const float* W = Wo1 + (size_t)(l * 2 * HH + HH) * HH;
        float a0 = 0.f, a1 = 0.f, a2 = 0.f, a3 = 0.f;
#pragma unroll 8
        for (int kk = 0; kk < 32; kk++) {
            a0 += bufA[kk] * W[kk * HH + tid];
            a1 += bufA[kk + 32] * W[(kk + 32) * HH + tid];
            a2 += bufA[kk + 64] * W[(kk + 64) * HH + tid];
            a3 += bufA[kk + 96] * W[(kk + 96) * HH + tid];
        }
        float x1 = bufA[128 + tid] + bo1[l * HH + tid] + (a0 + a1) + (a2 + a3);
        bufA[256 + tid] = fmaxf(x1, 0.f);
    }
    __syncthreads();

    // --- o = g @ Wo2 + bo2; y = h_i + o; LayerNorm; write h ---
    float y = 0.f;
    if (tid < LL) {
        const float* W = Wo2 + (size_t)l * HH * HH;
        float a0 = 0.f, a1 = 0.f, a2 = 0.f, a3 = 0.f;
#pragma unroll 8
        for (int kk = 0; kk < 32; kk++) {
            a0 += bufA[256 + kk] * W[kk * HH + tid];
            a1 += bufA[256 + kk + 32] * W[(kk + 32) * HH + tid];
            a2 += bufA[256 + kk + 64] * W[(kk + 64) * HH + tid];
            a3 += bufA[256 + kk + 96] * W[(kk + 96) * HH + tid];
        }
        y = h_i[tid] + bo2[l * HH + tid] + (a0 + a1) + (a2 + a3);
        float s = y;
#pragma unroll
        for (int d = 1; d < 64; d <<= 1) s += __shfl_xor(s, d);
        if (lane == 0) bufB[wv] = s;
    }
    __syncthreads();
    float mu = (bufB[0] + bufB[1]) * (1.f / HH);
    __syncthreads();
    if (tid < LL) {
        float d = y - mu;
        float s2 = d * d;
#pragma unroll
        for (int dd = 1; dd < 64; dd <<= 1) s2 += __shfl_xor(s2, dd);
        if (lane == 0) bufB[4 + wv] = s2;
    }
    __syncthreads();
    if (tid < LL) {
        float var = (bufB[4] + bufB[5]) * (1.f / HH);
        float vm = val_s[i] > 0.f ? 1.f : 0.f;
        float hv = ((y - mu) * rsqrtf(var + 1e-5f) * ln_g[l * HH + tid] + ln_b[l * HH + tid]) * vm;
        hout[(size_t)bi * HH + tid] = hv;
        if (hcopy) hcopy[(size_t)bi * HH + tid] = hv;
    }
}

// ---------------- decoder ----------------
__global__ __launch_bounds__(HH) void k_dec(const float* __restrict__ hist, const float* __restrict__ mask,
                                            const float* __restrict__ h, const float* __restrict__ hg,
                                            const float* __restrict__ hb, const float* __restrict__ Wh1,
                                            const float* __restrict__ bh1, const float* __restrict__ Wh2,
                                            const float* __restrict__ bh2, float* __restrict__ out) {
    int b = blockIdx.x, t = threadIdx.x;
    const int N = D_IN + HH;  // 136
    __shared__ float red[HH], x_s[D_IN + HH], u_s[HH];
    red[t] = mask[b * LL + t];
    __syncthreads();
    for (int s = 64; s > 0; s >>= 1) { if (t < s) red[t] += red[t + s]; __syncthreads(); }
    int vc = (int)red[0];
    vc = min(max(vc, 1), LL);
    int last = vc - 1;
    __syncthreads();
    if (t < D_IN) x_s[t] = hist[(size_t)(b * LL + last) * D_IN + t];
    x_s[D_IN + t] = h[(size_t)(b * LL + last) * HH + t];
    __syncthreads();
    float ps = 0.f;
    for (int f = t; f < N; f += HH) ps += x_s[f];
    red[t] = ps;
    __syncthreads();
    for (int s = 64; s > 0; s >>= 1) { if (t < s) red[t] += red[t + s]; __syncthreads(); }
    float mu = red[0] / N;
    __syncthreads();
    ps = 0.f;
    for (int f = t; f < N; f += HH) { float d = x_s[f] - mu; ps += d * d; }
    red[t] = ps;
    __syncthreads();
    for (int s = 64; s > 0; s >>= 1) { if (t < s) red[t] += red[t + s]; __syncthreads(); }
    float var = red[0] / N;
    float rs = rsqrtf(var + 1e-5f);
    __syncthreads();
    for (int f = t; f < N; f += HH) x_s[f] = (x_s[f] - mu) * rs * hg[f] + hb[f];
    __syncthreads();
    float acc = bh1[t];
    for (int f = 0; f < N; f++) acc += x_s[f] * Wh1[f * HH + t];
    u_s[t] = fmaxf(acc, 0.f);
    __syncthreads();
    if (t < FUT * MDIM) {
        float o = bh2[t];
        for (int k = 0; k < HH; k++) o += u_s[k] * Wh2[k * FUT * MDIM + t];
        if (isnan(o)) o = 0.f;
        else if (isinf(o)) o = (o > 0.f) ? 1e4f : -1e4f;
        out[b * FUT * MDIM + t] = o;
    }
}

extern "C" void kernel_launch(void* const* d_in, const int* in_sizes, int n_in,
                              void* d_out, int out_size, void* d_ws, size_t ws_size,
                              hipStream_t stream) {
    const float* hist = (const float*)d_in[0];
    const float* mask = (const float*)d_in[1];
    const float* Wp  = (const float*)d_in[2];
    const float* bp  = (const float*)d_in[3];
    const float* We1 = (const float*)d_in[4];
    const float* be1 = (const float*)d_in[5];
    const float* We2 = (const float*)d_in[6];
    const float* be2 = (const float*)d_in[7];
    const float* Wa1 = (const float*)d_in[8];
    const float* ba1 = (const float*)d_in[9];
    const float* wa2 = (const float*)d_in[10];
    const float* ba2 = (const float*)d_in[11];
    const float* Wm1 = (const float*)d_in[12];
    const float* bm1 = (const float*)d_in[13];
    const float* Wm2 = (const float*)d_in[14];
    const float* bm2 = (const float*)d_in[15];
    const float* Wo1 = (const float*)d_in[16];
    const float* bo1 = (const float*)d_in[17];
    const float* Wo2 = (const float*)d_in[18];
    const float* bo2 = (const float*)d_in[19];
    const float* ln_g = (const float*)d_in[20];
    const float* ln_b = (const float*)d_in[21];
    const float* hg  = (const float*)d_in[22];
    const float* hb  = (const float*)d_in[23];
    const float* Wh1 = (const float*)d_in[24];
    const float* bh1 = (const float*)d_in[25];
    const float* Wh2 = (const float*)d_in[26];
    const float* bh2 = (const float*)d_in[27];
    float* out = (float*)d_out;

    float* ws = (float*)d_ws;
    float* ts_w  = ws; ws += BB * LL;
    float* h_w   = ws; ws += BB * LL * HH;
    float* da_w  = ws; ws += BB * LL * HH;
    short* AmT_w = (short*)ws; ws += NLAYER * HH * HH / 2;
    short* MmT_w = (short*)ws; ws += NLAYER * HH * HH / 2;
    float* ca_w  = ws; ws += NLAYER * HH;
    float* cm_w  = ws; ws += NLAYER * HH;

    k_ts<<<BB, LL, 0, stream>>>(hist, ts_w);
    k_h0<<<(BB * LL * HH + 255) / 256, 256, 0, stream>>>(hist, mask, Wp, bp, h_w);
    k_compose<<<NLAYER * (HH + 1), HH, 0, stream>>>(We2, be2, Wa1, ba1, Wm1, bm1, AmT_w, MmT_w, ca_w, cm_w);
    for (int l = 0; l < NLAYER; l++) {
        k_da<<<BB * LL, HH, 0, stream>>>(h_w, Wa1, da_w, l);
        float* hcopy = (l == NLAYER - 1) ? (out + BB * FUT * MDIM) : nullptr;
        k_attn<<<BB * LL, 256, 0, stream>>>(hist, mask, ts_w, h_w, da_w, AmT_w, MmT_w, ca_w, cm_w,
                                            Wa1, Wm1, wa2, ba2, Wm2, bm2, We1, be1,
                                            Wo1, bo1, Wo2, bo2, ln_g, ln_b, h_w, hcopy, l);
    }
    k_dec<<<BB, HH, 0, stream>>>(hist, mask, h_w, hg, hb, Wh1, bh1, Wh2, bh2, out);
}

// Round 4
// 298.357 us; speedup vs baseline: 5.6346x; 1.0685x over previous
//
#include <hip/hip_runtime.h>
#include <math.h>

#define BB 16
#define LL 128
#define D_IN 8
#define HH 128
#define NLAYER 2
#define FUT 12
#define MDIM 2

typedef __attribute__((ext_vector_type(8))) __bf16 bf16x8;
typedef __attribute__((ext_vector_type(8))) short short8v;
typedef __attribute__((ext_vector_type(4))) float f32x4;

#define MFMA_B16(A, B, C) __builtin_amdgcn_mfma_f32_16x16x32_bf16(A, B, C, 0, 0, 0)

static __device__ __forceinline__ short f2bf(float f) {
    union { float f; unsigned u; } v; v.f = f;
    unsigned r = v.u + 0x7FFFu + ((v.u >> 16) & 1u);
    return (short)(r >> 16);
}

static __device__ __forceinline__ float tanh_fast(float x) {
    float e = __expf(2.f * x);
    return 1.f - 2.f / (e + 1.f);
}

// ---------------- ts cumsum (inclusive) ----------------
__global__ __launch_bounds__(LL) void k_ts(const float* __restrict__ hist, float* __restrict__ ts) {
    int b = blockIdx.x, j = threadIdx.x;
    __shared__ float s[LL];
    s[j] = fmaxf(hist[(b * LL + j) * D_IN + 5], 0.f);
    __syncthreads();
    for (int d = 1; d < LL; d <<= 1) {
        float add = (j >= d) ? s[j - d] : 0.f;
        __syncthreads();
        s[j] += add;
        __syncthreads();
    }
    ts[b * LL + j] = s[j];
}

// ---------------- h0 = (hist @ Wp + bp) * vm ----------------
__global__ __launch_bounds__(256) void k_h0(const float* __restrict__ hist, const float* __restrict__ mask,
                                            const float* __restrict__ Wp, const float* __restrict__ bp,
                                            float* __restrict__ h) {
    int idx = blockIdx.x * 256 + threadIdx.x;
    if (idx >= BB * LL * HH) return;
    int k = idx & (HH - 1);
    int bi = idx >> 7;
    const float* hr = hist + (size_t)bi * D_IN;
    float acc = bp[k];
#pragma unroll
    for (int f = 0; f < D_IN; f++) acc += hr[f] * Wp[f * HH + k];
    float vm = mask[bi] > 0.f ? 1.f : 0.f;
    h[idx] = acc * vm;
}

// ---------------- composed matrices for BOTH layers, transposed bf16 ----------------
__global__ __launch_bounds__(HH) void k_compose(const float* __restrict__ We2, const float* __restrict__ be2,
                                                const float* __restrict__ Wa1, const float* __restrict__ ba1,
                                                const float* __restrict__ Wm1, const float* __restrict__ bm1,
                                                short* __restrict__ AmT, short* __restrict__ MmT,
                                                float* __restrict__ ca, float* __restrict__ cm) {
    int blk = blockIdx.x;
    int l = blk / (HH + 1);
    int p = blk % (HH + 1);
    int q = threadIdx.x;
    __shared__ float row[HH];
    const float* WaE = Wa1 + (size_t)(l * 3 * HH + 2 * HH) * HH;
    const float* WmE = Wm1 + (size_t)(l * 2 * HH + HH) * HH;
    if (p < HH) {
        row[q] = We2[(size_t)(l * HH + p) * HH + q];
        __syncthreads();
        float a = 0.f, m = 0.f;
        for (int k = 0; k < HH; k++) { float w = row[k]; a += w * WaE[k * HH + q]; m += w * WmE[k * HH + q]; }
        AmT[(size_t)l * HH * HH + q * HH + p] = f2bf(a);
        MmT[(size_t)l * HH * HH + q * HH + p] = f2bf(m);
    } else {
        row[q] = be2[l * HH + q];
        __syncthreads();
        float a = 0.f, m = 0.f;
        for (int k = 0; k < HH; k++) { float w = row[k]; a += w * WaE[k * HH + q]; m += w * WmE[k * HH + q]; }
        ca[l * HH + q] = a + ba1[l * HH + q];
        cm[l * HH + q] = m + bm1[l * HH + q];
    }
}

// ---------------- transpose+cast weights to bf16 [c][k] layout ----------------
__global__ __launch_bounds__(256) void k_wconv(const float* __restrict__ Wa1, const float* __restrict__ Wm1,
                                               const float* __restrict__ Wo1, const float* __restrict__ Wm2,
                                               const float* __restrict__ Wo2,
                                               short* __restrict__ WT4, short* __restrict__ WT3) {
    int blk = blockIdx.x;  // NLAYER*7
    int l = blk / 7, m = blk % 7;
    const float* src;
    switch (m) {
        case 0: src = Wa1 + (size_t)(l * 3 * HH) * HH; break;
        case 1: src = Wa1 + (size_t)(l * 3 * HH + HH) * HH; break;
        case 2: src = Wm1 + (size_t)(l * 2 * HH) * HH; break;
        case 3: src = Wo1 + (size_t)(l * 2 * HH) * HH; break;
        case 4: src = Wm2 + (size_t)l * HH * HH; break;
        case 5: src = Wo1 + (size_t)(l * 2 * HH + HH) * HH; break;
        default: src = Wo2 + (size_t)l * HH * HH; break;
    }
    short* dst = (m < 4) ? (WT4 + (size_t)(l * 4 + m) * HH * HH) : (WT3 + (size_t)(l * 3 + (m - 4)) * HH * HH);
    int tid = threadIdx.x;
#pragma unroll 4
    for (int e = 0; e < 64; e++) {
        int idx = e * 256 + tid;
        int c = idx >> 7, k = idx & (HH - 1);
        dst[c * HH + k] = f2bf(src[k * HH + c]);
    }
}

// ---------------- batched pre-projections via MFMA: base_a, da, base_m, oa ----------------
__global__ __launch_bounds__(256) void k_pre(const float* __restrict__ h, const short* __restrict__ WT4,
                                             const float* __restrict__ ca, const float* __restrict__ cm,
                                             float* __restrict__ base_a, float* __restrict__ da,
                                             float* __restrict__ base_m, float* __restrict__ oa, int l) {
    __shared__ __align__(16) short hA[32][136];
    const int tid = threadIdx.x, lane = tid & 63, wv = tid >> 6;
    const int lo = lane & 15, g4 = lane >> 4;
    const int r0 = blockIdx.x * 32;
    {
        int row = tid >> 3, cc = (tid & 7) * 16;
        const float* hr = h + (size_t)(r0 + row) * HH + cc;
        short8v pk;
#pragma unroll
        for (int e = 0; e < 8; e++) pk[e] = f2bf(hr[e]);
        *(short8v*)&hA[row][cc] = pk;
#pragma unroll
        for (int e = 0; e < 8; e++) pk[e] = f2bf(hr[8 + e]);
        *(short8v*)&hA[row][cc + 8] = pk;
    }
    __syncthreads();
    bf16x8 af[2][4];
#pragma unroll
    for (int mt = 0; mt < 2; mt++)
#pragma unroll
        for (int ks = 0; ks < 4; ks++)
            af[mt][ks] = *(const bf16x8*)&hA[mt * 16 + lo][ks * 32 + g4 * 8];
    const short* Wl = WT4 + (size_t)(l * 4 + wv) * HH * HH;
    float* dst;
    const float* bias = nullptr;
    if (wv == 0) { dst = base_a; bias = ca + l * HH; }
    else if (wv == 1) dst = da;
    else if (wv == 2) { dst = base_m; bias = cm + l * HH; }
    else dst = oa;
#pragma unroll
    for (int ct = 0; ct < 8; ct++) {
        int col = ct * 16 + lo;
        bf16x8 Bf[4];
#pragma unroll
        for (int ks = 0; ks < 4; ks++)
            Bf[ks] = *(const bf16x8*)(Wl + (size_t)col * HH + ks * 32 + g4 * 8);
        f32x4 acc[2];
        acc[0] = (f32x4){0.f, 0.f, 0.f, 0.f};
        acc[1] = (f32x4){0.f, 0.f, 0.f, 0.f};
#pragma unroll
        for (int ks = 0; ks < 4; ks++) {
            acc[0] = MFMA_B16(af[0][ks], Bf[ks], acc[0]);
            acc[1] = MFMA_B16(af[1][ks], Bf[ks], acc[1]);
        }
        float bv = bias ? bias[col] : 0.f;
#pragma unroll
        for (int mt = 0; mt < 2; mt++)
#pragma unroll
            for (int rg = 0; rg < 4; rg++)
                dst[(size_t)(r0 + mt * 16 + g4 * 4 + rg) * HH + col] = acc[mt][rg] + bv;
    }
}

// ---------------- attention core: one block per (b,i), writes v ----------------
__global__ __launch_bounds__(256, 4) void k_attn(
    const float* __restrict__ hist, const float* __restrict__ mask, const float* __restrict__ ts,
    const float* __restrict__ base_a_g, const float* __restrict__ base_m_g, const float* __restrict__ da,
    const short* __restrict__ AmT, const short* __restrict__ MmT,
    const float* __restrict__ wa2, const float* __restrict__ ba2,
    const float* __restrict__ We1, const float* __restrict__ be1,
    float* __restrict__ v_out, int l) {
    __shared__ __align__(16) short t_lds[LL][136];
    __shared__ float bufA[512];
    __shared__ float bufB[128];
    __shared__ float val_s[128], base_a[128], base_m[128], wa2_s[128];

    const int tid = threadIdx.x;
    const int lane = tid & 63;
    const int wv = tid >> 6;
    const int lo = lane & 15, g4 = lane >> 4;
    const int bi = blockIdx.x, b = bi >> 7, i = bi & (LL - 1);

    // --- B1 fragments (Amat^T bf16), issue early (L2) ---
    bf16x8 Bf[2][4];
#pragma unroll
    for (int ct = 0; ct < 2; ct++) {
        int col = wv * 32 + ct * 16 + lo;
#pragma unroll
        for (int ks = 0; ks < 4; ks++)
            Bf[ct][ks] = *(const bf16x8*)(AmT + (size_t)l * HH * HH + col * HH + ks * 32 + g4 * 8);
    }

    // --- stage ---
    const float* We1l = We1 + l * 4 * HH;
    bufA[tid] = We1l[tid];
    bufA[tid + 256] = We1l[tid + 256];
    if (tid < LL) {
        val_s[tid] = mask[b * LL + tid];
        wa2_s[tid] = wa2[l * HH + tid];
        bufB[tid] = be1[l * HH + tid];
        base_a[tid] = base_a_g[(size_t)bi * HH + tid];
        base_m[tid] = base_m_g[(size_t)bi * HH + tid];
    }
    __syncthreads();

    // --- per-thread edge features + t = relu(ef @ We1 + be1) -> LDS bf16 ---
    {
        int jj = tid & (LL - 1);
        const float* hri = hist + (size_t)(b * LL + i) * D_IN;
        const float* hrj = hist + (size_t)(b * LL + jj) * D_IN;
        float dlat = hri[0] - hrj[0], dlon = hri[1] - hrj[1];
        float ea = sqrtf(dlat * dlat + dlon * dlon + 1e-8f);
        float eb = fabsf(ts[b * LL + i] - ts[b * LL + jj]) * (1.f / 300.f);
        float ec = (hri[6] == hrj[6]) ? 1.f : 0.f;
        float ed = (jj == i) ? 1.f : 0.f;
#pragma unroll
        for (int pass = 0; pass < 8; pass++) {
            int r0 = ((tid >> 7) + pass * 2) * 8;
            short8v pk;
#pragma unroll
            for (int e = 0; e < 8; e++) {
                int r = r0 + e;
                float v = ea * bufA[r] + eb * bufA[128 + r] + ec * bufA[256 + r] + ed * bufA[384 + r] + bufB[r];
                pk[e] = f2bf(fmaxf(v, 0.f));
            }
            *(short8v*)&t_lds[jj][r0] = pk;
        }
    }

    // --- acc init from da (loads hide under t-compute) ---
    f32x4 acc[8][2];
    const float* da_b = da + (size_t)(b * LL) * HH;
#pragma unroll
    for (int jt = 0; jt < 8; jt++)
#pragma unroll
        for (int ct = 0; ct < 2; ct++)
#pragma unroll
            for (int rg = 0; rg < 4; rg++)
                acc[jt][ct][rg] = da_b[(size_t)(jt * 16 + g4 * 4 + rg) * HH + wv * 32 + ct * 16 + lo];
    __syncthreads();

    // --- GEMM1: U_a = t @ Amat ---
#pragma unroll
    for (int ks = 0; ks < 4; ks++) {
#pragma unroll
        for (int jh = 0; jh < 2; jh++) {
            bf16x8 tf[4];
#pragma unroll
            for (int m = 0; m < 4; m++)
                tf[m] = *(const bf16x8*)&t_lds[(jh * 4 + m) * 16 + lo][ks * 32 + g4 * 8];
#pragma unroll
            for (int m = 0; m < 4; m++) {
                acc[jh * 4 + m][0] = MFMA_B16(tf[m], Bf[0][ks], acc[jh * 4 + m][0]);
                acc[jh * 4 + m][1] = MFMA_B16(tf[m], Bf[1][ks], acc[jh * 4 + m][1]);
            }
        }
    }

    // --- preload B2 (Mmat^T) ---
#pragma unroll
    for (int ct = 0; ct < 2; ct++) {
        int col = wv * 32 + ct * 16 + lo;
#pragma unroll
        for (int ks = 0; ks < 4; ks++)
            Bf[ct][ks] = *(const bf16x8*)(MmT + (size_t)l * HH * HH + col * HH + ks * 32 + g4 * 8);
    }

    // --- tanh + att partials -> bufA ---
    {
        int k0 = wv * 32 + lo, k1 = k0 + 16;
        float ba0 = base_a[k0], ba1v = base_a[k1];
        float w0a = wa2_s[k0], w1a = wa2_s[k1];
#pragma unroll
        for (int jt = 0; jt < 8; jt++) {
#pragma unroll
            for (int rg = 0; rg < 4; rg++) {
                float p = tanh_fast(acc[jt][0][rg] + ba0) * w0a + tanh_fast(acc[jt][1][rg] + ba1v) * w1a;
                p += __shfl_xor(p, 1);
                p += __shfl_xor(p, 2);
                p += __shfl_xor(p, 4);
                p += __shfl_xor(p, 8);
                if (lo == 0) bufA[wv * LL + jt * 16 + g4 * 4 + rg] = p;
            }
        }
    }
    __syncthreads();

    // --- redundant per-wave softmax ---
    float w0, w1;
    {
        const float inv = 0.08838834764831845f;  // 1/sqrt(128)
        float ba2l = ba2[l];
        float vi = val_s[i];
        float a0 = (bufA[lane] + bufA[128 + lane] + bufA[256 + lane] + bufA[384 + lane] + ba2l) * inv;
        float a1 = (bufA[64 + lane] + bufA[192 + lane] + bufA[320 + lane] + bufA[448 + lane] + ba2l) * inv;
        if (!(val_s[lane] > 0.f) || !(vi > 0.f)) a0 = -1e9f;
        if (!(val_s[64 + lane] > 0.f) || !(vi > 0.f)) a1 = -1e9f;
        float m = fmaxf(a0, a1);
#pragma unroll
        for (int d = 1; d < 64; d <<= 1) m = fmaxf(m, __shfl_xor(m, d));
        float e0 = __expf(a0 - m), e1 = __expf(a1 - m);
        float s = e0 + e1;
#pragma unroll
        for (int d = 1; d < 64; d <<= 1) s += __shfl_xor(s, d);
        float rs = 1.f / s;
        w0 = e0 * rs;
        w1 = e1 * rs;
    }

    // --- GEMM2: U_m = t @ Mmat ---
#pragma unroll
    for (int jt = 0; jt < 8; jt++)
#pragma unroll
        for (int ct = 0; ct < 2; ct++)
#pragma unroll
            for (int rg = 0; rg < 4; rg++) acc[jt][ct][rg] = 0.f;
#pragma unroll
    for (int ks = 0; ks < 4; ks++) {
#pragma unroll
        for (int jh = 0; jh < 2; jh++) {
            bf16x8 tf[4];
#pragma unroll
            for (int m = 0; m < 4; m++)
                tf[m] = *(const bf16x8*)&t_lds[(jh * 4 + m) * 16 + lo][ks * 32 + g4 * 8];
#pragma unroll
            for (int m = 0; m < 4; m++) {
                acc[jh * 4 + m][0] = MFMA_B16(tf[m], Bf[0][ks], acc[jh * 4 + m][0]);
                acc[jh * 4 + m][1] = MFMA_B16(tf[m], Bf[1][ks], acc[jh * 4 + m][1]);
            }
        }
    }

    // --- weighted relu-msg sum over j; write v directly ---
    {
        int k0 = wv * 32 + lo;
        float bm0 = base_m[k0], bm1v = base_m[k0 + 16];
        float mac0 = 0.f, mac1 = 0.f;
#pragma unroll
        for (int jt = 0; jt < 8; jt++) {
#pragma unroll
            for (int rg = 0; rg < 4; rg++) {
                int j = jt * 16 + g4 * 4 + rg;
                float wj = (jt < 4) ? __shfl(w0, j) : __shfl(w1, j - 64);
                mac0 += wj * fmaxf(acc[jt][0][rg] + bm0, 0.f);
                mac1 += wj * fmaxf(acc[jt][1][rg] + bm1v, 0.f);
            }
        }
        mac0 += __shfl_xor(mac0, 16);
        mac0 += __shfl_xor(mac0, 32);
        mac1 += __shfl_xor(mac1, 16);
        mac1 += __shfl_xor(mac1, 32);
        if (g4 == 0) {
            v_out[(size_t)bi * HH + wv * 32 + lo] = mac0;
            v_out[(size_t)bi * HH + wv * 32 + 16 + lo] = mac1;
        }
    }
}

// ---------------- batched post: agg -> x1 -> y, LayerNorm (MFMA chain) ----------------
__global__ __launch_bounds__(256) void k_post(
    const float* __restrict__ v, const float* __restrict__ oa, const float* __restrict__ h,
    const float* __restrict__ mask, const short* __restrict__ WT3,
    const float* __restrict__ bm2, const float* __restrict__ bo1, const float* __restrict__ bo2,
    const float* __restrict__ ln_g, const float* __restrict__ ln_b,
    float* __restrict__ hout, float* __restrict__ hcopy, int l) {
    __shared__ __align__(16) short xA[32][136];
    __shared__ __align__(16) short iA[32][136];
    __shared__ float red[2][4][32];
    const int tid = threadIdx.x, lane = tid & 63, wv = tid >> 6;
    const int lo = lane & 15, g4 = lane >> 4;
    const int r0 = blockIdx.x * 32;

    // preload epilogue operands early
    float oaR[2][2][4], hR[2][2][4], vmR[2][4];
    float bm2R[2], bo1R[2], bo2R[2], gR[2], bR[2];
#pragma unroll
    for (int ct = 0; ct < 2; ct++) {
        int c = wv * 32 + ct * 16 + lo;
        bm2R[ct] = bm2[l * HH + c];
        bo1R[ct] = bo1[l * HH + c];
        bo2R[ct] = bo2[l * HH + c];
        gR[ct] = ln_g[l * HH + c];
        bR[ct] = ln_b[l * HH + c];
    }
#pragma unroll
    for (int mt = 0; mt < 2; mt++)
#pragma unroll
        for (int rg = 0; rg < 4; rg++) {
            int r = r0 + mt * 16 + g4 * 4 + rg;
            vmR[mt][rg] = mask[r];
#pragma unroll
            for (int ct = 0; ct < 2; ct++) {
                int c = wv * 32 + ct * 16 + lo;
                oaR[mt][ct][rg] = oa[(size_t)r * HH + c];
                hR[mt][ct][rg] = h[(size_t)r * HH + c];
            }
        }

    // stage v -> xA bf16
    {
        int row = tid >> 3, cc = (tid & 7) * 16;
        const float* vr = v + (size_t)(r0 + row) * HH + cc;
        short8v pk;
#pragma unroll
        for (int e = 0; e < 8; e++) pk[e] = f2bf(vr[e]);
        *(short8v*)&xA[row][cc] = pk;
#pragma unroll
        for (int e = 0; e < 8; e++) pk[e] = f2bf(vr[8 + e]);
        *(short8v*)&xA[row][cc + 8] = pk;
    }
    __syncthreads();

    bf16x8 af[2][4], Bf[2][4];
    f32x4 acc[2][2];

    // ---- GEMM A: agg = v @ Wm2^T + bm2 -> iA ----
    {
        const short* W = WT3 + (size_t)(l * 3 + 0) * HH * HH;
#pragma unroll
        for (int mt = 0; mt < 2; mt++)
#pragma unroll
            for (int ks = 0; ks < 4; ks++)
                af[mt][ks] = *(const bf16x8*)&xA[mt * 16 + lo][ks * 32 + g4 * 8];
#pragma unroll
        for (int ct = 0; ct < 2; ct++) {
            int col = wv * 32 + ct * 16 + lo;
#pragma unroll
            for (int ks = 0; ks < 4; ks++)
                Bf[ct][ks] = *(const bf16x8*)(W + (size_t)col * HH + ks * 32 + g4 * 8);
        }
#pragma unroll
        for (int mt = 0; mt < 2; mt++)
#pragma unroll
            for (int ct = 0; ct < 2; ct++) acc[mt][ct] = (f32x4){0.f, 0.f, 0.f, 0.f};
#pragma unroll
        for (int ks = 0; ks < 4; ks++)
#pragma unroll
            for (int mt = 0; mt < 2; mt++) {
                acc[mt][0] = MFMA_B16(af[mt][ks], Bf[0][ks], acc[mt][0]);
                acc[mt][1] = MFMA_B16(af[mt][ks], Bf[1][ks], acc[mt][1]);
            }
#pragma unroll
        for (int mt = 0; mt < 2; mt++)
#pragma unroll
            for (int ct = 0; ct < 2; ct++)
#pragma unroll
                for (int rg = 0; rg < 4; rg++)
                    iA[mt * 16 + g4 * 4 + rg][wv * 32 + ct * 16 + lo] = f2bf(acc[mt][ct][rg] + bm2R[ct]);
    }
    __syncthreads();

    // ---- GEMM B: x1 = relu(agg @ Wo1H^T + oa + bo1) -> xA ----
    {
        const short* W = WT3 + (size_t)(l * 3 + 1) * HH * HH;
#pragma unroll
        for (int mt = 0; mt < 2; mt++)
#pragma unroll
            for (int ks = 0; ks < 4; ks++)
                af[mt][ks] = *(const bf16x8*)&iA[mt * 16 + lo][ks * 32 + g4 * 8];
#pragma unroll
        for (int ct = 0; ct < 2; ct++) {
            int col = wv * 32 + ct * 16 + lo;
#pragma unroll
            for (int ks = 0; ks < 4; ks++)
                Bf[ct][ks] = *(const bf16x8*)(W + (size_t)col * HH + ks * 32 + g4 * 8);
        }
#pragma unroll
        for (int mt = 0; mt < 2; mt++)
#pragma unroll
            for (int ct = 0; ct < 2; ct++) acc[mt][ct] = (f32x4){0.f, 0.f, 0.f, 0.f};
#pragma unroll
        for (int ks = 0; ks < 4; ks++)
#pragma unroll
            for (int mt = 0; mt < 2; mt++) {
                acc[mt][0] = MFMA_B16(af[mt][ks], Bf[0][ks], acc[mt][0]);
                acc[mt][1] = MFMA_B16(af[mt][ks], Bf[1][ks], acc[mt][1]);
            }
#pragma unroll
        for (int mt = 0; mt < 2; mt++)
#pragma unroll
            for (int ct = 0; ct < 2; ct++)
#pragma unroll
                for (int rg = 0; rg < 4; rg++)
                    xA[mt * 16 + g4 * 4 + rg][wv * 32 + ct * 16 + lo] =
                        f2bf(fmaxf(acc[mt][ct][rg] + oaR[mt][ct][rg] + bo1R[ct], 0.f));
    }
    __syncthreads();

    // ---- GEMM C: y = x1 @ Wo2^T + bo2 + h; LayerNorm ----
    float y[2][2][4];
    {
        const short* W = WT3 + (size_t)(l * 3 + 2) * HH * HH;
#pragma unroll
        for (int mt = 0; mt < 2; mt++)
#pragma unroll
            for (int ks = 0; ks < 4; ks++)
                af[mt][ks] = *(const bf16x8*)&xA[mt * 16 + lo][ks * 32 + g4 * 8];
#pragma unroll
        for (int ct = 0; ct < 2; ct++) {
            int col = wv * 32 + ct * 16 + lo;
#pragma unroll
            for (int ks = 0; ks < 4; ks++)
                Bf[ct][ks] = *(const bf16x8*)(W + (size_t)col * HH + ks * 32 + g4 * 8);
        }
#pragma unroll
        for (int mt = 0; mt < 2; mt++)
#pragma unroll
            for (int ct = 0; ct < 2; ct++) acc[mt][ct] = (f32x4){0.f, 0.f, 0.f, 0.f};
#pragma unroll
        for (int ks = 0; ks < 4; ks++)
#pragma unroll
            for (int mt = 0; mt < 2; mt++) {
                acc[mt][0] = MFMA_B16(af[mt][ks], Bf[0][ks], acc[mt][0]);
                acc[mt][1] = MFMA_B16(af[mt][ks], Bf[1][ks], acc[mt][1]);
            }
#pragma unroll
        for (int mt = 0; mt < 2; mt++)
#pragma unroll
            for (int ct = 0; ct < 2; ct++)
#pragma unroll
                for (int rg = 0; rg < 4; rg++)
                    y[mt][ct][rg] = acc[mt][ct][rg] + bo2R[ct] + hR[mt][ct][rg];
    }
    // row partial sums across this wave's 32 cols
#pragma unroll
    for (int mt = 0; mt < 2; mt++)
#pragma unroll
        for (int rg = 0; rg < 4; rg++) {
            float s = y[mt][0][rg] + y[mt][1][rg];
            float s2 = y[mt][0][rg] * y[mt][0][rg] + y[mt][1][rg] * y[mt][1][rg];
#pragma unroll
            for (int d = 1; d < 16; d <<= 1) { s += __shfl_xor(s, d); s2 += __shfl_xor(s2, d); }
            if (lo == 0) {
                red[0][wv][mt * 16 + g4 * 4 + rg] = s;
                red[1][wv][mt * 16 + g4 * 4 + rg] = s2;
            }
        }
    __syncthreads();
#pragma unroll
    for (int mt = 0; mt < 2; mt++)
#pragma unroll
        for (int rg = 0; rg < 4; rg++) {
            int rl = mt * 16 + g4 * 4 + rg;
            float mu = (red[0][0][rl] + red[0][1][rl] + red[0][2][rl] + red[0][3][rl]) * (1.f / HH);
            float ex2 = (red[1][0][rl] + red[1][1][rl] + red[1][2][rl] + red[1][3][rl]) * (1.f / HH);
            float var = ex2 - mu * mu;
            float rs = rsqrtf(var + 1e-5f);
            float vm = vmR[mt][rg] > 0.f ? 1.f : 0.f;
            int r = r0 + rl;
#pragma unroll
            for (int ct = 0; ct < 2; ct++) {
                int c = wv * 32 + ct * 16 + lo;
                float hv = ((y[mt][ct][rg] - mu) * rs * gR[ct] + bR[ct]) * vm;
                hout[(size_t)r * HH + c] = hv;
                if (hcopy) hcopy[(size_t)r * HH + c] = hv;
            }
        }
}

// ---------------- decoder ----------------
__global__ __launch_bounds__(HH) void k_dec(const float* __restrict__ hist, const float* __restrict__ mask,
                                            const float* __restrict__ h, const float* __restrict__ hg,
                                            const float* __restrict__ hb, const float* __restrict__ Wh1,
                                            const float* __restrict__ bh1, const float* __restrict__ Wh2,
                                            const float* __restrict__ bh2, float* __restrict__ out) {
    int b = blockIdx.x, t = threadIdx.x;
    const int N = D_IN + HH;  // 136
    __shared__ float red[HH], x_s[D_IN + HH], u_s[HH];
    red[t] = mask[b * LL + t];
    __syncthreads();
    for (int s = 64; s > 0; s >>= 1) { if (t < s) red[t] += red[t + s]; __syncthreads(); }
    int vc = (int)red[0];
    vc = min(max(vc, 1), LL);
    int last = vc - 1;
    __syncthreads();
    if (t < D_IN) x_s[t] = hist[(size_t)(b * LL + last) * D_IN + t];
    x_s[D_IN + t] = h[(size_t)(b * LL + last) * HH + t];
    __syncthreads();
    float ps = 0.f;
    for (int f = t; f < N; f += HH) ps += x_s[f];
    red[t] = ps;
    __syncthreads();
    for (int s = 64; s > 0; s >>= 1) { if (t < s) red[t] += red[t + s]; __syncthreads(); }
    float mu = red[0] / N;
    __syncthreads();
    ps = 0.f;
    for (int f = t; f < N; f += HH) { float d = x_s[f] - mu; ps += d * d; }
    red[t] = ps;
    __syncthreads();
    for (int s = 64; s > 0; s >>= 1) { if (t < s) red[t] += red[t + s]; __syncthreads(); }
    float var = red[0] / N;
    float rs = rsqrtf(var + 1e-5f);
    __syncthreads();
    for (int f = t; f < N; f += HH) x_s[f] = (x_s[f] - mu) * rs * hg[f] + hb[f];
    __syncthreads();
    float acc = bh1[t];
    for (int f = 0; f < N; f++) acc += x_s[f] * Wh1[f * HH + t];
    u_s[t] = fmaxf(acc, 0.f);
    __syncthreads();
    if (t < FUT * MDIM) {
        float o = bh2[t];
        for (int k = 0; k < HH; k++) o += u_s[k] * Wh2[k * FUT * MDIM + t];
        if (isnan(o)) o = 0.f;
        else if (isinf(o)) o = (o > 0.f) ? 1e4f : -1e4f;
        out[b * FUT * MDIM + t] = o;
    }
}

extern "C" void kernel_launch(void* const* d_in, const int* in_sizes, int n_in,
                              void* d_out, int out_size, void* d_ws, size_t ws_size,
                              hipStream_t stream) {
    const float* hist = (const float*)d_in[0];
    const float* mask = (const float*)d_in[1];
    const float* Wp  = (const float*)d_in[2];
    const float* bp  = (const float*)d_in[3];
    const float* We1 = (const float*)d_in[4];
    const float* be1 = (const float*)d_in[5];
    const float* We2 = (const float*)d_in[6];
    const float* be2 = (const float*)d_in[7];
    const float* Wa1 = (const float*)d_in[8];
    const float* ba1 = (const float*)d_in[9];
    const float* wa2 = (const float*)d_in[10];
    const float* ba2 = (const float*)d_in[11];
    const float* Wm1 = (const float*)d_in[12];
    const float* bm1 = (const float*)d_in[13];
    const float* Wm2 = (const float*)d_in[14];
    const float* bm2 = (const float*)d_in[15];
    const float* Wo1 = (const float*)d_in[16];
    const float* bo1 = (const float*)d_in[17];
    const float* Wo2 = (const float*)d_in[18];
    const float* bo2 = (const float*)d_in[19];
    const float* ln_g = (const float*)d_in[20];
    const float* ln_b = (const float*)d_in[21];
    const float* hg  = (const float*)d_in[22];
    const float* hb  = (const float*)d_in[23];
    const float* Wh1 = (const float*)d_in[24];
    const float* bh1 = (const float*)d_in[25];
    const float* Wh2 = (const float*)d_in[26];
    const float* bh2 = (const float*)d_in[27];
    float* out = (float*)d_out;

    float* ws = (float*)d_ws;
    float* ts_w   = ws; ws += BB * LL;
    float* h_w    = ws; ws += BB * LL * HH;
    float* da_w   = ws; ws += BB * LL * HH;
    float* ba_w   = ws; ws += BB * LL * HH;   // base_a
    float* bm_w   = ws; ws += BB * LL * HH;   // base_m
    float* oa_w   = ws; ws += BB * LL * HH;
    float* v_w    = ws; ws += BB * LL * HH;
    float* ca_w   = ws; ws += NLAYER * HH;
    float* cm_w   = ws; ws += NLAYER * HH;
    short* AmT_w  = (short*)ws; ws += NLAYER * HH * HH / 2;
    short* MmT_w  = (short*)ws; ws += NLAYER * HH * HH / 2;
    short* WT4_w  = (short*)ws; ws += NLAYER * 4 * HH * HH / 2;
    short* WT3_w  = (short*)ws; ws += NLAYER * 3 * HH * HH / 2;

    k_ts<<<BB, LL, 0, stream>>>(hist, ts_w);
    k_h0<<<(BB * LL * HH + 255) / 256, 256, 0, stream>>>(hist, mask, Wp, bp, h_w);
    k_compose<<<NLAYER * (HH + 1), HH, 0, stream>>>(We2, be2, Wa1, ba1, Wm1, bm1, AmT_w, MmT_w, ca_w, cm_w);
    k_wconv<<<NLAYER * 7, 256, 0, stream>>>(Wa1, Wm1, Wo1, Wm2, Wo2, WT4_w, WT3_w);
    for (int l = 0; l < NLAYER; l++) {
        k_pre<<<BB * LL / 32, 256, 0, stream>>>(h_w, WT4_w, ca_w, cm_w, ba_w, da_w, bm_w, oa_w, l);
        k_attn<<<BB * LL, 256, 0, stream>>>(hist, mask, ts_w, ba_w, bm_w, da_w, AmT_w, MmT_w,
                                            wa2, ba2, We1, be1, v_w, l);
        float* hcopy = (l == NLAYER - 1) ? (out + BB * FUT * MDIM) : nullptr;
        k_post<<<BB * LL / 32, 256, 0, stream>>>(v_w, oa_w, h_w, mask, WT3_w, bm2, bo1, bo2,
                                                 ln_g, ln_b, h_w, hcopy, l);
    }
    k_dec<<<BB, HH, 0, stream>>>(hist, mask, h_w, hg, hb, Wh1, bh1, Wh2, bh2, out);
}